// Round 2
// baseline (6021.098 us; speedup 1.0000x reference)
//
#include <hip/hip_runtime.h>

namespace {

constexpr int B = 32, H = 512, L = 2, T = 20, V = 10000, S = 49;
constexpr int NB = 256, NT = 512;   // persistent grid: <=1 block/CU guaranteed resident

__device__ __forceinline__ float sigf(float x) { return 1.0f / (1.0f + expf(-x)); }
__device__ __forceinline__ float dot4(float4 a, float4 b) {
  return a.x*b.x + a.y*b.y + a.z*b.z + a.w*b.w;
}

struct KParams {
  const float *chan, *pooled, *embed, *Wq, *bq, *Wk, *bk, *Wv, *bv,
              *Wih, *Whh, *bih, *bhh, *projW, *projb, *hattW, *hattb;
  const int* sos;
  float* out;
  float* ws;    // data region (cnt lives before it)
  int* cnt;     // grid-barrier counter (zeroed via hipMemsetAsync)
};

// ---- capture-safe grid barrier: monotonic epoch, device-scope atomics ----
__device__ __forceinline__ void gsync(int* cnt, int target) {
  __syncthreads();
  if (threadIdx.x == 0) {
    __threadfence();                  // release: all prior writes visible device-wide
    atomicAdd(cnt, 1);
    unsigned spins = 0;
    while (atomicAdd(cnt, 0) < target) {       // coherent device-scope read
      __builtin_amdgcn_s_sleep(8);
      if (++spins > (1u << 20)) break;         // ~0.2s bail-out: fail, don't hang
    }
    __threadfence();                  // acquire: invalidate stale cache lines
  }
  __syncthreads();
}

// ===================== persistent-kernel phase bodies =====================

__device__ __forceinline__ void stage64k(const float* __restrict__ src,
                                         float* smem, int tid) {
  const float4* g = (const float4*)src;
  float4* s4 = (float4*)smem;
  for (int i = tid; i < 4096; i += NT) s4[i] = g[i];
}

// LSTM: each block owns 2 hi rows; 256-thread-half mapping identical to the
// proven lstm_kernel (ko16 x rr4 x bh4, 8 batches) -> identical numerics.
__device__ __forceinline__ void lstm_do(
    const float* __restrict__ x, const float* __restrict__ hp,
    float* __restrict__ cp, const float* __restrict__ Wih,
    const float* __restrict__ Whh, const float* __restrict__ bih,
    const float* __restrict__ bhh, float* __restrict__ ho,
    float* smem, int blk, int tid) {
  int tl = tid & 255, hh = tid >> 8;
  int ko = tl & 15, rr = (tl >> 4) & 3, bh = tl >> 6;
  int hi = blk * 2 + hh;
  stage64k(x, smem, tid);
  __syncthreads();
  float acc[8];
#pragma unroll
  for (int j = 0; j < 8; ++j) acc[j] = 0.f;
  {
    const float* wrow = Wih + ((size_t)rr * H + hi) * H;
    float4 w[8];
#pragma unroll
    for (int kk = 0; kk < 8; ++kk) w[kk] = *(const float4*)&wrow[kk * 64 + ko * 4];
#pragma unroll
    for (int j = 0; j < 8; ++j) {
      const float* xb = smem + (bh * 8 + j) * 512;
#pragma unroll
      for (int kk = 0; kk < 8; ++kk)
        acc[j] += dot4(*(const float4*)&xb[kk * 64 + ko * 4], w[kk]);
    }
  }
  __syncthreads();
  stage64k(hp, smem, tid);
  __syncthreads();
  {
    const float* wrow = Whh + ((size_t)rr * H + hi) * H;
    float4 w[8];
#pragma unroll
    for (int kk = 0; kk < 8; ++kk) w[kk] = *(const float4*)&wrow[kk * 64 + ko * 4];
#pragma unroll
    for (int j = 0; j < 8; ++j) {
      const float* xb = smem + (bh * 8 + j) * 512;
#pragma unroll
      for (int kk = 0; kk < 8; ++kk)
        acc[j] += dot4(*(const float4*)&xb[kk * 64 + ko * 4], w[kk]);
    }
  }
  __syncthreads();   // all LDS reads done before gbuf overwrite
#pragma unroll
  for (int j = 0; j < 8; ++j) {
    acc[j] += __shfl_xor(acc[j], 1);
    acc[j] += __shfl_xor(acc[j], 2);
    acc[j] += __shfl_xor(acc[j], 4);
    acc[j] += __shfl_xor(acc[j], 8);
  }
  float* gbuf = smem;   // 256 floats reused
  if (ko == 0) {
    float bias = bih[rr * H + hi] + bhh[rr * H + hi];
#pragma unroll
    for (int j = 0; j < 8; ++j) gbuf[hh * 128 + rr * 32 + bh * 8 + j] = acc[j] + bias;
  }
  __syncthreads();
  if (tid < 64) {
    int hs = tid >> 5, b = tid & 31;
    int hi2 = blk * 2 + hs;
    const float* gb = gbuf + hs * 128;
    float gi = gb[b], gf = gb[32 + b], gg = gb[64 + b], go = gb[96 + b];
    float c2 = sigf(gf) * cp[b * H + hi2] + sigf(gi) * tanhf(gg);
    ho[b * H + hi2] = sigf(go) * tanhf(c2);
    cp[b * H + hi2] = c2;
  }
}

// proj: 313 chunks of 32 v-rows over 256 blocks (blocks 0..56 do two).
__device__ __forceinline__ void proj_do(
    const float* __restrict__ x, float* __restrict__ dst,
    const float* __restrict__ projW, const float* __restrict__ projb,
    float* smem, int blk, int tid) {
  stage64k(x, smem, tid);
  __syncthreads();
  int ko = tid & 15, vl = tid >> 4;   // vl 0..31
  for (int chunk = blk; chunk < 313; chunk += NB) {
    int v = chunk * 32 + vl;
    if (v < V) {
      const float* wrow = projW + (size_t)v * H;
      float4 w[8];
#pragma unroll
      for (int kk = 0; kk < 8; ++kk) w[kk] = *(const float4*)&wrow[kk * 64 + ko * 4];
      float acc[32];
#pragma unroll
      for (int b = 0; b < 32; ++b) acc[b] = 0.f;
      for (int b = 0; b < 32; ++b) {
        const float* xb = smem + b * 512;
#pragma unroll
        for (int kk = 0; kk < 8; ++kk)
          acc[b] += dot4(*(const float4*)&xb[kk * 64 + ko * 4], w[kk]);
      }
#pragma unroll
      for (int b = 0; b < 32; ++b) {
        acc[b] += __shfl_xor(acc[b], 1);
        acc[b] += __shfl_xor(acc[b], 2);
        acc[b] += __shfl_xor(acc[b], 4);
        acc[b] += __shfl_xor(acc[b], 8);
      }
      if (ko == 0) {
        float bias = projb[v];
        for (int b = 0; b < 32; ++b) dst[(size_t)b * V + v] = acc[b] + bias;
      }
    }
  }
}

// q: 32 units (2 lg x 16 jg of 32 j); runs on blocks 57..88 after their proj chunk.
__device__ __forceinline__ void q_do(
    const float* __restrict__ hmid, const float* __restrict__ Wq,
    const float* __restrict__ bq, float* __restrict__ q,
    float* smem, int u, int tid) {
  int lg = u & 1, jg = u >> 1;
  __syncthreads();                       // done reading proj's staged x
  stage64k(hmid + (size_t)lg * B * H, smem, tid);
  __syncthreads();
  int ko = tid & 15, jl = tid >> 4;
  int j = jg * 32 + jl;
  const float* wrow = Wq + (size_t)j * H;
  float4 w[8];
#pragma unroll
  for (int kk = 0; kk < 8; ++kk) w[kk] = *(const float4*)&wrow[kk * 64 + ko * 4];
  float acc[32];
#pragma unroll
  for (int b = 0; b < 32; ++b) acc[b] = 0.f;
  for (int b = 0; b < 32; ++b) {
    const float* xb = smem + b * 512;
#pragma unroll
    for (int kk = 0; kk < 8; ++kk)
      acc[b] += dot4(*(const float4*)&xb[kk * 64 + ko * 4], w[kk]);
  }
#pragma unroll
  for (int b = 0; b < 32; ++b) {
    acc[b] += __shfl_xor(acc[b], 1);
    acc[b] += __shfl_xor(acc[b], 2);
    acc[b] += __shfl_xor(acc[b], 4);
    acc[b] += __shfl_xor(acc[b], 8);
  }
  if (ko == 0) {
    float bias = bq[j];
    for (int b = 0; b < 32; ++b)
      q[(size_t)(lg * 32 + b) * H + j] = tanhf(acc[b] + bias);
  }
}

// sattn: one block per lb (blocks 0..63).
__device__ __forceinline__ void sattn_do(
    const float* __restrict__ q, const float* __restrict__ keysT,
    const float* __restrict__ valuesT, const float* __restrict__ hmid,
    float* __restrict__ cat, float* smem, int lb, int tid) {
  float* qv = smem;            // 4 chunks of 132 (128+4 skew)
  float* scl = smem + 544;
  float* wts = smem + 608;
  int b = lb & 31;
  qv[(tid >> 7) * 132 + (tid & 127)] = q[(size_t)lb * H + tid];
  __syncthreads();
  int kq = tid & 3, sl = tid >> 2;
  float acc = 0.f;
  if (sl < S) {
    const float* kr = keysT + ((size_t)b * S + sl) * H + kq * 128;
    const float* qr = &qv[kq * 132];
    for (int k = 0; k < 128; k += 4)
      acc += dot4(*(const float4*)&qr[k], *(const float4*)&kr[k]);
  }
  acc += __shfl_xor(acc, 1);
  acc += __shfl_xor(acc, 2);
  if (kq == 0 && sl < S) scl[sl] = acc * (1.0f / 7.0f);
  __syncthreads();
  if (tid < 64) {
    float sc = (tid < S) ? scl[tid] : -3.4e38f;
    float m = sc;
    for (int o = 32; o > 0; o >>= 1) m = fmaxf(m, __shfl_xor(m, o));
    float e = (tid < S) ? expf(sc - m) : 0.f;
    float sum = e;
    for (int o = 32; o > 0; o >>= 1) sum += __shfl_xor(sum, o);
    if (tid < S) wts[tid] = e / sum;
  }
  __syncthreads();
  float a0 = 0.f;
  for (int s = 0; s < S; ++s)
    a0 += wts[s] * valuesT[((size_t)b * S + s) * H + tid];
  cat[(size_t)lb * 1024 + tid] = a0;
  cat[(size_t)lb * 1024 + 512 + tid] = hmid[(size_t)lb * H + tid];
}

// argmax+embed: one block per batch (blocks 64..95). Lowest-index-on-tie.
__device__ __forceinline__ void argmax_do(
    const float* __restrict__ lgts, const float* __restrict__ embed,
    float* __restrict__ emb, float* smem, int b, int tid) {
  float* sv = smem;
  int* si = (int*)(smem + 512);
  float best = -3.4e38f;
  int bi = 0x7fffffff;
  for (int it = 0; it < 5; ++it) {
    int v0 = it * 2048 + tid * 4;
    if (v0 < V) {
      float4 lv = *(const float4*)&lgts[(size_t)b * V + v0];
      if (lv.x > best) { best = lv.x; bi = v0; }
      if (lv.y > best) { best = lv.y; bi = v0 + 1; }
      if (lv.z > best) { best = lv.z; bi = v0 + 2; }
      if (lv.w > best) { best = lv.w; bi = v0 + 3; }
    }
  }
  sv[tid] = best; si[tid] = bi;
  __syncthreads();
  for (int st = 256; st > 0; st >>= 1) {
    if (tid < st) {
      float ov = sv[tid + st]; int oi = si[tid + st];
      if (ov > sv[tid] || (ov == sv[tid] && oi < si[tid])) { sv[tid] = ov; si[tid] = oi; }
    }
    __syncthreads();
  }
  int idx = si[0];
  emb[(size_t)b * H + tid] = embed[(size_t)idx * H + tid];
}

// hatt: blocks 0..63 (lbg4 x jg16, 32 j x 16 lb each).
__device__ __forceinline__ void hatt_do(
    const float* __restrict__ cat, const float* __restrict__ hattW,
    const float* __restrict__ hattb, float* __restrict__ h,
    float* smem, int blk, int tid) {
  int lbg = blk & 3, jg = blk >> 2;
  stage64k(cat + (size_t)lbg * 16 * 1024, smem, tid);
  __syncthreads();
  int ko = tid & 15, jl = tid >> 4;
  int j = jg * 32 + jl;
  const float* wrow = hattW + (size_t)j * 1024;
  float4 w[16];
#pragma unroll
  for (int kk = 0; kk < 16; ++kk) w[kk] = *(const float4*)&wrow[kk * 64 + ko * 4];
  float acc[16];
#pragma unroll
  for (int lb = 0; lb < 16; ++lb) acc[lb] = 0.f;
  for (int lb = 0; lb < 16; ++lb) {
    const float* cb = smem + lb * 1024;
#pragma unroll
    for (int kk = 0; kk < 16; ++kk)
      acc[lb] += dot4(*(const float4*)&cb[kk * 64 + ko * 4], w[kk]);
  }
#pragma unroll
  for (int lb = 0; lb < 16; ++lb) {
    acc[lb] += __shfl_xor(acc[lb], 1);
    acc[lb] += __shfl_xor(acc[lb], 2);
    acc[lb] += __shfl_xor(acc[lb], 4);
    acc[lb] += __shfl_xor(acc[lb], 8);
  }
  if (ko == 0) {
    float bias = hattb[j];
    for (int lb = 0; lb < 16; ++lb)
      h[(size_t)(lbg * 16 + lb) * H + j] = tanhf(acc[lb] + bias);
  }
}

// ===================== the persistent kernel (plain launch) ===============
__global__ __launch_bounds__(NT, 4) void persist(KParams p) {
  __shared__ __align__(16) float smem[16384];   // 64 KB
  const int blk = blockIdx.x, tid = threadIdx.x;
  int* cnt = p.cnt;
  int ep = 0;

  float* keysT   = p.ws;
  float* valuesT = keysT + B * S * H;
  float* emb     = valuesT + B * S * H;
  float* h       = emb + B * H;
  float* c       = h + L * B * H;
  float* hmid    = c + L * B * H;
  float* cat     = hmid + L * B * H;
  float* q       = cat + L * B * 1024;
  float* logits  = q + L * B * H;      // reserved (fallback layout compat)
  float* slog    = logits + B * V;

  // ---- phase A: keys/values + state init ----
  {
    float* ch = smem;                  // 64*52
    float* wk = smem + 64 * 52;        // 49*52
    float* wv = wk + 49 * 52;
    int b = blk >> 3, dt = blk & 7;
    for (int i = tid; i < 49 * 49; i += NT) {
      int s = i / 49, j = i % 49;
      wk[s * 52 + j] = p.Wk[i]; wv[s * 52 + j] = p.Wv[i];
    }
    for (int i = tid; i < 64 * 49; i += NT) {
      int d = i / 49, j = i % 49;
      ch[d * 52 + j] = p.chan[((size_t)b * 512 + dt * 64 + d) * S + j];
    }
    __syncthreads();
    int dl = tid >> 3, sq = tid & 7;
    for (int s = sq; s < S; s += 8) {
      float ak = p.bk[s], av = p.bv[s];
      for (int j = 0; j < 49; ++j) {
        float cv = ch[dl * 52 + j];
        ak += cv * wk[s * 52 + j];
        av += cv * wv[s * 52 + j];
      }
      int d = dt * 64 + dl;
      keysT[((size_t)b * S + s) * H + d] = tanhf(ak);
      valuesT[((size_t)b * S + s) * H + d] = tanhf(av);
    }
    int idx = blk * NT + tid;
    if (idx < L * B * H) {
      float pv = p.pooled[idx & (B * H - 1)];
      h[idx] = pv; c[idx] = pv;
      if (idx < B * H) emb[idx] = p.embed[(size_t)p.sos[0] * H + (idx & (H - 1))];
    }
  }
  gsync(cnt, (++ep) * NB);

  // ---- phase B: proj of <SOS> embedding -> slog[0] ----
  proj_do(emb, slog, p.projW, p.projb, smem, blk, tid);
  gsync(cnt, (++ep) * NB);

  // ---- main T-loop ----
#pragma unroll 1
  for (int t = 0; t < T - 1; ++t) {
    lstm_do(emb, h, c, p.Wih, p.Whh, p.bih, p.bhh, hmid, smem, blk, tid);
    gsync(cnt, (++ep) * NB);
    lstm_do(hmid, h + B * H, c + B * H, p.Wih + 4 * H * H, p.Whh + 4 * H * H,
            p.bih + 4 * H, p.bhh + 4 * H, hmid + B * H, smem, blk, tid);
    gsync(cnt, (++ep) * NB);
    proj_do(hmid + B * H, slog + (size_t)(t + 1) * B * V, p.projW, p.projb,
            smem, blk, tid);
    if (t < T - 2 && blk >= 57 && blk < 89)
      q_do(hmid, p.Wq, p.bq, q, smem, blk - 57, tid);
    gsync(cnt, (++ep) * NB);
    if (t < T - 2) {   // last step: q/sattn/argmax/hatt outputs are dead
      if (blk < 64)
        sattn_do(q, keysT, valuesT, hmid, cat, smem, blk, tid);
      else if (blk < 96)
        argmax_do(slog + (size_t)(t + 1) * B * V, p.embed, emb, smem, blk - 64, tid);
      gsync(cnt, (++ep) * NB);
      if (blk < 64) hatt_do(cat, p.hattW, p.hattb, h, smem, blk, tid);
      gsync(cnt, (++ep) * NB);
    }
  }

  // ---- finalize: slog[t][b*V+v] -> out[b][v][t] ----
  for (int i = blk * NT + tid; i < B * V; i += NB * NT) {
    float vals[T];
#pragma unroll
    for (int t = 0; t < T; ++t) vals[t] = slog[(size_t)t * (B * V) + i];
#pragma unroll
    for (int t = 0; t < T; t += 4)
      *(float4*)&p.out[(size_t)i * T + t] =
          make_float4(vals[t], vals[t + 1], vals[t + 2], vals[t + 3]);
  }
}

// ===================== fallback: proven multi-kernel path =================

__global__ __launch_bounds__(256) void kv_kernel(
    const float* __restrict__ chan,
    const float* __restrict__ Wk, const float* __restrict__ bk,
    const float* __restrict__ Wv, const float* __restrict__ bv,
    float* __restrict__ keysT, float* __restrict__ valuesT) {
  __shared__ float ch[64][52];
  __shared__ float wk[49][52], wv[49][52];
  int b = blockIdx.x >> 3, dt = blockIdx.x & 7;
  int tid = threadIdx.x;
  for (int i = tid; i < 49 * 49; i += 256) {
    int s = i / 49, j = i % 49;
    wk[s][j] = Wk[i]; wv[s][j] = Wv[i];
  }
  for (int i = tid; i < 64 * 49; i += 256) {
    int d = i / 49, j = i % 49;
    ch[d][j] = chan[((size_t)b * 512 + dt * 64 + d) * S + j];
  }
  __syncthreads();
  int dl = tid >> 2, sq = tid & 3;
  for (int s = sq; s < S; s += 4) {
    float ak = bk[s], av = bv[s];
    for (int j = 0; j < 49; ++j) {
      float cv = ch[dl][j];
      ak += cv * wk[s][j];
      av += cv * wv[s][j];
    }
    int d = dt * 64 + dl;
    keysT[((size_t)b * S + s) * H + d] = tanhf(ak);
    valuesT[((size_t)b * S + s) * H + d] = tanhf(av);
  }
}

__global__ void init_kernel(const float* __restrict__ pooled,
                            const float* __restrict__ embed,
                            const int* __restrict__ sos,
                            float* __restrict__ emb, float* __restrict__ h,
                            float* __restrict__ c) {
  int idx = blockIdx.x * 256 + threadIdx.x;
  float p = pooled[idx & (B * H - 1)];
  h[idx] = p;
  c[idx] = p;
  if (idx < B * H) emb[idx] = embed[sos[0] * H + (idx & (H - 1))];
}

__global__ __launch_bounds__(256) void lstm_kernel(
    const float* __restrict__ x, const float* __restrict__ hprev,
    const float* __restrict__ cprev,
    const float* __restrict__ Wih, const float* __restrict__ Whh,
    const float* __restrict__ bih, const float* __restrict__ bhh,
    float* __restrict__ hout, float* __restrict__ cout) {
  __shared__ __align__(16) float smem[32 * 512];
  int tid = threadIdx.x;
  int hi = blockIdx.x;
  int ko = tid & 15, rr = (tid >> 4) & 3, bh = tid >> 6;
  {
    const float4* xg = (const float4*)x;
    float4* s4 = (float4*)smem;
    for (int i = tid; i < 4096; i += 256) s4[i] = xg[i];
  }
  __syncthreads();
  float acc[8];
#pragma unroll
  for (int j = 0; j < 8; ++j) acc[j] = 0.f;
  {
    const float* wrow = Wih + ((size_t)rr * H + hi) * H;
    float4 w[8];
#pragma unroll
    for (int kk = 0; kk < 8; ++kk) w[kk] = *(const float4*)&wrow[kk * 64 + ko * 4];
#pragma unroll
    for (int j = 0; j < 8; ++j) {
      const float* xb = smem + (bh * 8 + j) * 512;
#pragma unroll
      for (int kk = 0; kk < 8; ++kk)
        acc[j] += dot4(*(const float4*)&xb[kk * 64 + ko * 4], w[kk]);
    }
  }
  __syncthreads();
  {
    const float4* hg = (const float4*)hprev;
    float4* s4 = (float4*)smem;
    for (int i = tid; i < 4096; i += 256) s4[i] = hg[i];
  }
  __syncthreads();
  {
    const float* wrow = Whh + ((size_t)rr * H + hi) * H;
    float4 w[8];
#pragma unroll
    for (int kk = 0; kk < 8; ++kk) w[kk] = *(const float4*)&wrow[kk * 64 + ko * 4];
#pragma unroll
    for (int j = 0; j < 8; ++j) {
      const float* xb = smem + (bh * 8 + j) * 512;
#pragma unroll
      for (int kk = 0; kk < 8; ++kk)
        acc[j] += dot4(*(const float4*)&xb[kk * 64 + ko * 4], w[kk]);
    }
  }
  __syncthreads();
#pragma unroll
  for (int j = 0; j < 8; ++j) {
    acc[j] += __shfl_xor(acc[j], 1);
    acc[j] += __shfl_xor(acc[j], 2);
    acc[j] += __shfl_xor(acc[j], 4);
    acc[j] += __shfl_xor(acc[j], 8);
  }
  float* gbuf = smem;
  if (ko == 0) {
    float bias = bih[rr * H + hi] + bhh[rr * H + hi];
#pragma unroll
    for (int j = 0; j < 8; ++j) gbuf[rr * 32 + bh * 8 + j] = acc[j] + bias;
  }
  __syncthreads();
  if (tid < 32) {
    int b = tid;
    float gi = gbuf[b], gf = gbuf[32 + b], gg = gbuf[64 + b], go = gbuf[96 + b];
    float c2 = sigf(gf) * cprev[b * H + hi] + sigf(gi) * tanhf(gg);
    hout[b * H + hi] = sigf(go) * tanhf(c2);
    cout[b * H + hi] = c2;
  }
}

__global__ __launch_bounds__(256) void projq_kernel(
    const float* __restrict__ xin,
    const float* __restrict__ projW, const float* __restrict__ projb,
    float* __restrict__ logits, float* __restrict__ ocol, int direct, int tcol,
    const float* __restrict__ hmid_all, const float* __restrict__ Wq,
    const float* __restrict__ bq, float* __restrict__ q) {
  __shared__ __align__(16) float xs[32 * 512];
  int blk = blockIdx.x, tid = threadIdx.x;
  int ko = tid & 15, vl = tid >> 4;
  if (blk < 625) {
    {
      const float4* xg = (const float4*)xin;
      float4* s4 = (float4*)xs;
      for (int i = tid; i < 4096; i += 256) s4[i] = xg[i];
    }
    __syncthreads();
    int v = blk * 16 + vl;
    const float* wrow = projW + (size_t)v * H;
    float4 w[8];
#pragma unroll
    for (int kk = 0; kk < 8; ++kk) w[kk] = *(const float4*)&wrow[kk * 64 + ko * 4];
    float acc[32];
#pragma unroll
    for (int b = 0; b < 32; ++b) acc[b] = 0.f;
    for (int b = 0; b < 32; ++b) {
      const float* xb = xs + b * 512;
#pragma unroll
      for (int kk = 0; kk < 8; ++kk)
        acc[b] += dot4(*(const float4*)&xb[kk * 64 + ko * 4], w[kk]);
    }
#pragma unroll
    for (int b = 0; b < 32; ++b) {
      acc[b] += __shfl_xor(acc[b], 1);
      acc[b] += __shfl_xor(acc[b], 2);
      acc[b] += __shfl_xor(acc[b], 4);
      acc[b] += __shfl_xor(acc[b], 8);
    }
    if (ko == 0) {
      float bias = projb[v];
      for (int b = 0; b < 32; ++b) {
        float r = acc[b] + bias;
        logits[b * V + v] = r;
        if (direct) ocol[((size_t)b * V + v) * T + tcol] = r;
        else        ocol[b * V + v] = r;
      }
    }
  } else {
    int b2 = blk - 625;
    int lg = b2 & 1, jg = b2 >> 1;
    {
      const float4* xg = (const float4*)(hmid_all + lg * 32 * H);
      float4* s4 = (float4*)xs;
      for (int i = tid; i < 4096; i += 256) s4[i] = xg[i];
    }
    __syncthreads();
    int j = jg * 16 + vl;
    const float* wrow = Wq + (size_t)j * H;
    float4 w[8];
#pragma unroll
    for (int kk = 0; kk < 8; ++kk) w[kk] = *(const float4*)&wrow[kk * 64 + ko * 4];
    float acc[32];
#pragma unroll
    for (int b = 0; b < 32; ++b) acc[b] = 0.f;
    for (int b = 0; b < 32; ++b) {
      const float* xb = xs + b * 512;
#pragma unroll
      for (int kk = 0; kk < 8; ++kk)
        acc[b] += dot4(*(const float4*)&xb[kk * 64 + ko * 4], w[kk]);
    }
#pragma unroll
    for (int b = 0; b < 32; ++b) {
      acc[b] += __shfl_xor(acc[b], 1);
      acc[b] += __shfl_xor(acc[b], 2);
      acc[b] += __shfl_xor(acc[b], 4);
      acc[b] += __shfl_xor(acc[b], 8);
    }
    if (ko == 0) {
      float bias = bq[j];
      for (int b = 0; b < 32; ++b)
        q[(lg * 32 + b) * H + j] = tanhf(acc[b] + bias);
    }
  }
}

__global__ __launch_bounds__(256) void sattn_kernel(
    const float* __restrict__ q, const float* __restrict__ keysT,
    const float* __restrict__ valuesT, const float* __restrict__ hmid,
    float* __restrict__ cat) {
  __shared__ __align__(16) float qv[528];
  __shared__ float scl[64];
  __shared__ float wts[64];
  int lb = blockIdx.x, tid = threadIdx.x;
  int b = lb & 31;
  {
    int c0 = tid, c1 = tid + 256;
    qv[(c0 >> 7) * 132 + (c0 & 127)] = q[lb * H + c0];
    qv[(c1 >> 7) * 132 + (c1 & 127)] = q[lb * H + c1];
  }
  __syncthreads();
  int kq = tid & 3, sl = tid >> 2;
  float acc = 0.f;
  if (sl < S) {
    const float* kr = keysT + ((size_t)b * S + sl) * H + kq * 128;
    const float* qr = &qv[kq * 132];
    for (int k = 0; k < 128; k += 4)
      acc += dot4(*(const float4*)&qr[k], *(const float4*)&kr[k]);
  }
  acc += __shfl_xor(acc, 1);
  acc += __shfl_xor(acc, 2);
  if (kq == 0 && sl < S) scl[sl] = acc * (1.0f / 7.0f);
  __syncthreads();
  if (tid < 64) {
    float sc = (tid < S) ? scl[tid] : -3.4e38f;
    float m = sc;
    for (int o = 32; o > 0; o >>= 1) m = fmaxf(m, __shfl_xor(m, o));
    float e = (tid < S) ? expf(sc - m) : 0.f;
    float sum = e;
    for (int o = 32; o > 0; o >>= 1) sum += __shfl_xor(sum, o);
    if (tid < S) wts[tid] = e / sum;
  }
  __syncthreads();
  float acc0 = 0.f, acc1 = 0.f;
  for (int s = 0; s < S; ++s) {
    float w = wts[s];
    const float* vr = valuesT + ((size_t)b * S + s) * H;
    acc0 += w * vr[tid];
    acc1 += w * vr[tid + 256];
  }
  cat[lb * 1024 + tid] = acc0;
  cat[lb * 1024 + tid + 256] = acc1;
  cat[lb * 1024 + 512 + tid] = hmid[lb * H + tid];
  cat[lb * 1024 + 768 + tid] = hmid[lb * H + tid + 256];
}

__global__ __launch_bounds__(256) void hattarg_kernel(
    const float* __restrict__ cat, const float* __restrict__ hattW,
    const float* __restrict__ hattb, float* __restrict__ h,
    const float* __restrict__ logits, const float* __restrict__ embed,
    float* __restrict__ emb) {
  __shared__ __align__(16) float smem[16 * 1024];
  int blk = blockIdx.x, tid = threadIdx.x;
  if (blk < 128) {
    int lbg = blk & 3, jg = blk >> 2;
    {
      const float4* cg2 = (const float4*)(cat + lbg * 16 * 1024);
      float4* s4 = (float4*)smem;
      for (int i = tid; i < 4096; i += 256) s4[i] = cg2[i];
    }
    __syncthreads();
    int ko = tid & 15, jl = tid >> 4;
    int j = jg * 16 + jl;
    const float* wrow = hattW + (size_t)j * 1024;
    float4 w[16];
#pragma unroll
    for (int kk = 0; kk < 16; ++kk) w[kk] = *(const float4*)&wrow[kk * 64 + ko * 4];
    float acc[16];
#pragma unroll
    for (int lb = 0; lb < 16; ++lb) acc[lb] = 0.f;
    for (int lb = 0; lb < 16; ++lb) {
      const float* cb = smem + lb * 1024;
#pragma unroll
      for (int kk = 0; kk < 16; ++kk)
        acc[lb] += dot4(*(const float4*)&cb[kk * 64 + ko * 4], w[kk]);
    }
#pragma unroll
    for (int lb = 0; lb < 16; ++lb) {
      acc[lb] += __shfl_xor(acc[lb], 1);
      acc[lb] += __shfl_xor(acc[lb], 2);
      acc[lb] += __shfl_xor(acc[lb], 4);
      acc[lb] += __shfl_xor(acc[lb], 8);
    }
    if (ko == 0) {
      float bias = hattb[j];
      for (int lb = 0; lb < 16; ++lb)
        h[(lbg * 16 + lb) * H + j] = tanhf(acc[lb] + bias);
    }
  } else {
    int b = blk - 128;
    float* sv = smem;
    int* si = (int*)(smem + 256);
    float best = -3.4e38f;
    int bi = 0x7fffffff;
    for (int it = 0; it < 10; ++it) {
      int v0 = it * 1024 + tid * 4;
      if (v0 < V) {
        float4 lv = *(const float4*)&logits[b * V + v0];
        if (lv.x > best) { best = lv.x; bi = v0; }
        if (lv.y > best) { best = lv.y; bi = v0 + 1; }
        if (lv.z > best) { best = lv.z; bi = v0 + 2; }
        if (lv.w > best) { best = lv.w; bi = v0 + 3; }
      }
    }
    sv[tid] = best; si[tid] = bi;
    __syncthreads();
    for (int st = 128; st > 0; st >>= 1) {
      if (tid < st) {
        float ov = sv[tid + st]; int oi = si[tid + st];
        if (ov > sv[tid] || (ov == sv[tid] && oi < si[tid])) { sv[tid] = ov; si[tid] = oi; }
      }
      __syncthreads();
    }
    int idx = si[0];
    for (int i = tid; i < H; i += 256) emb[b * H + i] = embed[(size_t)idx * H + i];
  }
}

__global__ __launch_bounds__(256) void finalize_kernel(
    const float* __restrict__ slog, float* __restrict__ outp) {
  int idx = blockIdx.x * 256 + threadIdx.x;
  float vals[T];
#pragma unroll
  for (int t = 0; t < T; ++t) vals[t] = slog[(size_t)t * (B * V) + idx];
#pragma unroll
  for (int t = 0; t < T; t += 4)
    *(float4*)&outp[(size_t)idx * T + t] =
        make_float4(vals[t], vals[t + 1], vals[t + 2], vals[t + 3]);
}

}  // namespace

extern "C" void kernel_launch(void* const* d_in, const int* in_sizes, int n_in,
                              void* d_out, int out_size, void* d_ws, size_t ws_size,
                              hipStream_t stream) {
  (void)in_sizes; (void)n_in; (void)out_size;
  const float* chan   = (const float*)d_in[0];
  const float* pooled = (const float*)d_in[1];
  const float* embed  = (const float*)d_in[2];
  const float* Wq     = (const float*)d_in[3];
  const float* bq     = (const float*)d_in[4];
  const float* Wk     = (const float*)d_in[5];
  const float* bk     = (const float*)d_in[6];
  const float* Wv     = (const float*)d_in[7];
  const float* bv     = (const float*)d_in[8];
  const float* Wih    = (const float*)d_in[9];
  const float* Whh    = (const float*)d_in[10];
  const float* bih    = (const float*)d_in[11];
  const float* bhh    = (const float*)d_in[12];
  const float* projW  = (const float*)d_in[13];
  const float* projb  = (const float*)d_in[14];
  const float* hattW  = (const float*)d_in[15];
  const float* hattb  = (const float*)d_in[16];
  const int*   sos    = (const int*)d_in[17];

  float* out = (float*)d_out;
  int*   cnt = (int*)d_ws;                 // grid-barrier counter (first 256 B)
  float* ws  = (float*)d_ws + 64;          // data region

  float* keysT   = ws;
  float* valuesT = keysT + B * S * 512;
  float* emb     = valuesT + B * S * 512;
  float* h       = emb + B * H;
  float* c       = h + L * B * H;
  float* hmid    = c + L * B * H;
  float* cat     = hmid + L * B * H;
  float* q       = cat + L * B * 1024;
  float* logits  = q + L * B * H;
  float* slog    = logits + B * V;

  size_t need_floats = 64 + (size_t)(slog - ws) + (size_t)T * B * V;
  bool fits = ws_size >= need_floats * sizeof(float);

  if (fits) {
    hipMemsetAsync(d_ws, 0, 256, stream);  // zero barrier counter (capture-legal)
    KParams p = {chan, pooled, embed, Wq, bq, Wk, bk, Wv, bv,
                 Wih, Whh, bih, bhh, projW, projb, hattW, hattb,
                 sos, out, ws, cnt};
    persist<<<NB, NT, 0, stream>>>(p);
    return;
  }

  // -------- fallback: previous verified multi-kernel path --------
  size_t base_floats = (size_t)(slog - ws) + 64;
  bool staged = ws_size >= (base_floats + (size_t)T * B * V) * sizeof(float);

  kv_kernel<<<256, 256, 0, stream>>>(chan, Wk, bk, Wv, bv, keysT, valuesT);
  init_kernel<<<(L * B * H) / 256, 256, 0, stream>>>(pooled, embed, sos, emb, h, c);
  {
    float* oc = staged ? slog : out;
    projq_kernel<<<625, 256, 0, stream>>>(emb, projW, projb, logits, oc,
                                          staged ? 0 : 1, 0,
                                          hmid, Wq, bq, q);
  }
  for (int t = 0; t < T - 1; ++t) {
    float* oc = staged ? (slog + (size_t)(t + 1) * B * V) : out;
    lstm_kernel<<<512, 256, 0, stream>>>(emb, h, c, Wih, Whh, bih, bhh, hmid, c);
    lstm_kernel<<<512, 256, 0, stream>>>(hmid, h + B * H, c + B * H,
                                         Wih + 4 * H * H, Whh + 4 * H * H,
                                         bih + 4 * H, bhh + 4 * H,
                                         hmid + B * H, c + B * H);
    projq_kernel<<<689, 256, 0, stream>>>(hmid + B * H, projW, projb, logits, oc,
                                          staged ? 0 : 1, t + 1,
                                          hmid, Wq, bq, q);
    sattn_kernel<<<L * B, 256, 0, stream>>>(q, keysT, valuesT, hmid, cat);
    hattarg_kernel<<<160, 256, 0, stream>>>(cat, hattW, hattb, h,
                                            logits, embed, emb);
  }
  if (staged) finalize_kernel<<<(B * V) / 256, 256, 0, stream>>>(slog, out);
}

// Round 4
// 4549.828 us; speedup vs baseline: 1.3234x; 1.3234x over previous
//
#include <hip/hip_runtime.h>

namespace {

constexpr int B = 32, H = 512, L = 2, T = 20, V = 10000, S = 49;
constexpr int NB = 256, NT = 512;   // persistent grid: 1 block/CU, all resident

__device__ __forceinline__ float sigf(float x) { return 1.0f / (1.0f + expf(-x)); }
__device__ __forceinline__ float dot4(float4 a, float4 b) {
  return a.x*b.x + a.y*b.y + a.z*b.z + a.w*b.w;
}

// Coherent (agent-scope, L1/L2-bypassing) loads for cross-phase activations.
__device__ __forceinline__ float cohf(const float* p) {
  return __hip_atomic_load(p, __ATOMIC_RELAXED, __HIP_MEMORY_SCOPE_AGENT);
}

struct KParams {
  const float *chan, *pooled, *embed, *Wq, *bq, *Wk, *bk, *Wv, *bv,
              *Wih, *Whh, *bih, *bhh, *projW, *projb, *hattW, *hattb;
  const int* sos;
  float* out;
  float* ws;    // data region
  int* bar;     // barrier region: 16 leaves @ stride 16 ints, root @ [256]
};

// ---- grid barrier: release-only fence (L2 writeback, NO invalidate), ----
// ---- 16-leaf tree arrival, relaxed-atomic-load spin on root.          ----
__device__ __forceinline__ void gsync(int* bar, int ep, int blk) {
  __syncthreads();   // emits full waitcnt: all block's stores are in L2
  if (threadIdx.x == 0) {
    // release: write back this XCD's dirty L2 lines to the coherence point.
    __builtin_amdgcn_fence(__ATOMIC_RELEASE, "agent");
    int g = blk & 15;
    int r = __hip_atomic_fetch_add(&bar[g * 16], 1,
                                   __ATOMIC_RELAXED, __HIP_MEMORY_SCOPE_AGENT);
    if (r == ep * 16 - 1)   // last of this leaf's 16 blocks this epoch
      __hip_atomic_fetch_add(&bar[256], 1,
                             __ATOMIC_RELAXED, __HIP_MEMORY_SCOPE_AGENT);
    unsigned spins = 0;
    while (__hip_atomic_load(&bar[256], __ATOMIC_RELAXED,
                             __HIP_MEMORY_SCOPE_AGENT) < ep * 16) {
      __builtin_amdgcn_s_sleep(2);
      if (++spins > (1u << 22)) break;   // bail: fail verification, never hang
    }
  }
  __syncthreads();
}

// ===================== persistent-kernel phase bodies =====================

// Coherent 64 KB stage (8 B granules): cross-phase activations only.
__device__ __forceinline__ void stage64k(const float* __restrict__ src,
                                         float* smem, int tid) {
  const unsigned long long* g = (const unsigned long long*)src;
  unsigned long long* s8 = (unsigned long long*)smem;
  for (int i = tid; i < 8192; i += NT)
    s8[i] = __hip_atomic_load(g + i, __ATOMIC_RELAXED, __HIP_MEMORY_SCOPE_AGENT);
}

// LSTM: each block owns 2 hi rows; 256-thread-half mapping identical to the
// proven lstm_kernel (ko16 x rr4 x bh4, 8 batches) -> identical numerics.
__device__ __forceinline__ void lstm_do(
    const float* __restrict__ x, const float* __restrict__ hp,
    float* __restrict__ cp, const float* __restrict__ Wih,
    const float* __restrict__ Whh, const float* __restrict__ bih,
    const float* __restrict__ bhh, float* __restrict__ ho,
    float* smem, int blk, int tid) {
  int tl = tid & 255, hh = tid >> 8;
  int ko = tl & 15, rr = (tl >> 4) & 3, bh = tl >> 6;
  int hi = blk * 2 + hh;
  stage64k(x, smem, tid);
  __syncthreads();
  float acc[8];
#pragma unroll
  for (int j = 0; j < 8; ++j) acc[j] = 0.f;
  {
    const float* wrow = Wih + ((size_t)rr * H + hi) * H;   // normal: L2-warm
    float4 w[8];
#pragma unroll
    for (int kk = 0; kk < 8; ++kk) w[kk] = *(const float4*)&wrow[kk * 64 + ko * 4];
#pragma unroll
    for (int j = 0; j < 8; ++j) {
      const float* xb = smem + (bh * 8 + j) * 512;
#pragma unroll
      for (int kk = 0; kk < 8; ++kk)
        acc[j] += dot4(*(const float4*)&xb[kk * 64 + ko * 4], w[kk]);
    }
  }
  __syncthreads();
  stage64k(hp, smem, tid);
  __syncthreads();
  {
    const float* wrow = Whh + ((size_t)rr * H + hi) * H;
    float4 w[8];
#pragma unroll
    for (int kk = 0; kk < 8; ++kk) w[kk] = *(const float4*)&wrow[kk * 64 + ko * 4];
#pragma unroll
    for (int j = 0; j < 8; ++j) {
      const float* xb = smem + (bh * 8 + j) * 512;
#pragma unroll
      for (int kk = 0; kk < 8; ++kk)
        acc[j] += dot4(*(const float4*)&xb[kk * 64 + ko * 4], w[kk]);
    }
  }
  __syncthreads();   // all LDS reads done before gbuf overwrite
#pragma unroll
  for (int j = 0; j < 8; ++j) {
    acc[j] += __shfl_xor(acc[j], 1);
    acc[j] += __shfl_xor(acc[j], 2);
    acc[j] += __shfl_xor(acc[j], 4);
    acc[j] += __shfl_xor(acc[j], 8);
  }
  float* gbuf = smem;   // 256 floats reused
  if (ko == 0) {
    float bias = bih[rr * H + hi] + bhh[rr * H + hi];
#pragma unroll
    for (int j = 0; j < 8; ++j) gbuf[hh * 128 + rr * 32 + bh * 8 + j] = acc[j] + bias;
  }
  __syncthreads();
  if (tid < 64) {
    int hs = tid >> 5, b = tid & 31;
    int hi2 = blk * 2 + hs;
    const float* gb = gbuf + hs * 128;
    float gi = gb[b], gf = gb[32 + b], gg = gb[64 + b], go = gb[96 + b];
    float c2 = sigf(gf) * cohf(&cp[b * H + hi2]) + sigf(gi) * tanhf(gg);
    ho[b * H + hi2] = sigf(go) * tanhf(c2);
    cp[b * H + hi2] = c2;
  }
}

// proj: 313 chunks of 32 v-rows over 256 blocks (blocks 0..56 do two).
__device__ __forceinline__ void proj_do(
    const float* __restrict__ x, float* __restrict__ dst,
    const float* __restrict__ projW, const float* __restrict__ projb,
    float* smem, int blk, int tid) {
  stage64k(x, smem, tid);
  __syncthreads();
  int ko = tid & 15, vl = tid >> 4;   // vl 0..31
  for (int chunk = blk; chunk < 313; chunk += NB) {
    int v = chunk * 32 + vl;
    if (v < V) {
      const float* wrow = projW + (size_t)v * H;   // normal: L2-warm, fixed blk->rows
      float4 w[8];
#pragma unroll
      for (int kk = 0; kk < 8; ++kk) w[kk] = *(const float4*)&wrow[kk * 64 + ko * 4];
      float acc[32];
#pragma unroll
      for (int b = 0; b < 32; ++b) acc[b] = 0.f;
      for (int b = 0; b < 32; ++b) {
        const float* xb = smem + b * 512;
#pragma unroll
        for (int kk = 0; kk < 8; ++kk)
          acc[b] += dot4(*(const float4*)&xb[kk * 64 + ko * 4], w[kk]);
      }
#pragma unroll
      for (int b = 0; b < 32; ++b) {
        acc[b] += __shfl_xor(acc[b], 1);
        acc[b] += __shfl_xor(acc[b], 2);
        acc[b] += __shfl_xor(acc[b], 4);
        acc[b] += __shfl_xor(acc[b], 8);
      }
      if (ko == 0) {
        float bias = projb[v];
        for (int b = 0; b < 32; ++b) dst[(size_t)b * V + v] = acc[b] + bias;
      }
    }
  }
}

// q: 32 units (2 lg x 16 jg of 32 j); runs on blocks 57..88 after their proj chunk.
__device__ __forceinline__ void q_do(
    const float* __restrict__ hmid, const float* __restrict__ Wq,
    const float* __restrict__ bq, float* __restrict__ q,
    float* smem, int u, int tid) {
  int lg = u & 1, jg = u >> 1;
  __syncthreads();                       // done reading proj's staged x
  stage64k(hmid + (size_t)lg * B * H, smem, tid);
  __syncthreads();
  int ko = tid & 15, jl = tid >> 4;
  int j = jg * 32 + jl;
  const float* wrow = Wq + (size_t)j * H;
  float4 w[8];
#pragma unroll
  for (int kk = 0; kk < 8; ++kk) w[kk] = *(const float4*)&wrow[kk * 64 + ko * 4];
  float acc[32];
#pragma unroll
  for (int b = 0; b < 32; ++b) acc[b] = 0.f;
  for (int b = 0; b < 32; ++b) {
    const float* xb = smem + b * 512;
#pragma unroll
    for (int kk = 0; kk < 8; ++kk)
      acc[b] += dot4(*(const float4*)&xb[kk * 64 + ko * 4], w[kk]);
  }
#pragma unroll
  for (int b = 0; b < 32; ++b) {
    acc[b] += __shfl_xor(acc[b], 1);
    acc[b] += __shfl_xor(acc[b], 2);
    acc[b] += __shfl_xor(acc[b], 4);
    acc[b] += __shfl_xor(acc[b], 8);
  }
  if (ko == 0) {
    float bias = bq[j];
    for (int b = 0; b < 32; ++b)
      q[(size_t)(lg * 32 + b) * H + j] = tanhf(acc[b] + bias);
  }
}

// sattn: one block per lb (blocks 0..63).
__device__ __forceinline__ void sattn_do(
    const float* __restrict__ q, const float* __restrict__ keysT,
    const float* __restrict__ valuesT, const float* __restrict__ hmid,
    float* __restrict__ cat, float* smem, int lb, int tid) {
  float* qv = smem;            // 4 chunks of 132 (128+4 skew)
  float* scl = smem + 544;
  float* wts = smem + 608;
  int b = lb & 31;
  qv[(tid >> 7) * 132 + (tid & 127)] = cohf(&q[(size_t)lb * H + tid]);
  __syncthreads();
  int kq = tid & 3, sl = tid >> 2;
  float acc = 0.f;
  if (sl < S) {
    const float* kr = keysT + ((size_t)b * S + sl) * H + kq * 128;  // normal: L2-warm
    const float* qr = &qv[kq * 132];
    for (int k = 0; k < 128; k += 4)
      acc += dot4(*(const float4*)&qr[k], *(const float4*)&kr[k]);
  }
  acc += __shfl_xor(acc, 1);
  acc += __shfl_xor(acc, 2);
  if (kq == 0 && sl < S) scl[sl] = acc * (1.0f / 7.0f);
  __syncthreads();
  if (tid < 64) {
    float sc = (tid < S) ? scl[tid] : -3.4e38f;
    float m = sc;
    for (int o = 32; o > 0; o >>= 1) m = fmaxf(m, __shfl_xor(m, o));
    float e = (tid < S) ? expf(sc - m) : 0.f;
    float sum = e;
    for (int o = 32; o > 0; o >>= 1) sum += __shfl_xor(sum, o);
    if (tid < S) wts[tid] = e / sum;
  }
  __syncthreads();
  float a0 = 0.f;
  for (int s = 0; s < S; ++s)
    a0 += wts[s] * valuesT[((size_t)b * S + s) * H + tid];   // normal: L2-warm
  cat[(size_t)lb * 1024 + tid] = a0;
  cat[(size_t)lb * 1024 + 512 + tid] = cohf(&hmid[(size_t)lb * H + tid]);
}

// argmax+embed: one block per batch (blocks 64..95). Lowest-index-on-tie.
__device__ __forceinline__ void argmax_do(
    const float* __restrict__ lgts, const float* __restrict__ embed,
    float* __restrict__ emb, float* smem, int b, int tid) {
  float* sv = smem;
  int* si = (int*)(smem + 512);
  float best = -3.4e38f;
  int bi = 0x7fffffff;
  for (int it = 0; it < 5; ++it) {
    int v0 = it * 2048 + tid * 4;
    if (v0 < V) {
      // slog slot is write-once-then-read: per-line single-writer, fetched
      // fresh (never cached on this XCD before) or from own dirty L2.
      float4 lv = *(const float4*)&lgts[(size_t)b * V + v0];
      if (lv.x > best) { best = lv.x; bi = v0; }
      if (lv.y > best) { best = lv.y; bi = v0 + 1; }
      if (lv.z > best) { best = lv.z; bi = v0 + 2; }
      if (lv.w > best) { best = lv.w; bi = v0 + 3; }
    }
  }
  sv[tid] = best; si[tid] = bi;
  __syncthreads();
  for (int st = 256; st > 0; st >>= 1) {
    if (tid < st) {
      float ov = sv[tid + st]; int oi = si[tid + st];
      if (ov > sv[tid] || (ov == sv[tid] && oi < si[tid])) { sv[tid] = ov; si[tid] = oi; }
    }
    __syncthreads();
  }
  int idx = si[0];
  emb[(size_t)b * H + tid] = embed[(size_t)idx * H + tid];
}

// hatt: blocks 0..63 (lbg4 x jg16, 32 j x 16 lb each).
__device__ __forceinline__ void hatt_do(
    const float* __restrict__ cat, const float* __restrict__ hattW,
    const float* __restrict__ hattb, float* __restrict__ h,
    float* smem, int blk, int tid) {
  int lbg = blk & 3, jg = blk >> 2;
  stage64k(cat + (size_t)lbg * 16 * 1024, smem, tid);
  __syncthreads();
  int ko = tid & 15, jl = tid >> 4;
  int j = jg * 32 + jl;
  const float* wrow = hattW + (size_t)j * 1024;   // normal: L2-warm
  float4 w[16];
#pragma unroll
  for (int kk = 0; kk < 16; ++kk) w[kk] = *(const float4*)&wrow[kk * 64 + ko * 4];
  float acc[16];
#pragma unroll
  for (int lb = 0; lb < 16; ++lb) acc[lb] = 0.f;
  for (int lb = 0; lb < 16; ++lb) {
    const float* cb = smem + lb * 1024;
#pragma unroll
    for (int kk = 0; kk < 16; ++kk)
      acc[lb] += dot4(*(const float4*)&cb[kk * 64 + ko * 4], w[kk]);
  }
#pragma unroll
  for (int lb = 0; lb < 16; ++lb) {
    acc[lb] += __shfl_xor(acc[lb], 1);
    acc[lb] += __shfl_xor(acc[lb], 2);
    acc[lb] += __shfl_xor(acc[lb], 4);
    acc[lb] += __shfl_xor(acc[lb], 8);
  }
  if (ko == 0) {
    float bias = hattb[j];
    for (int lb = 0; lb < 16; ++lb)
      h[(size_t)(lbg * 16 + lb) * H + j] = tanhf(acc[lb] + bias);
  }
}

// ===================== the persistent kernel (plain launch) ===============
__global__ __launch_bounds__(NT, 4) void persist(KParams p) {
  __shared__ __align__(16) float smem[16384];   // 64 KB
  const int blk = blockIdx.x, tid = threadIdx.x;
  int* bar = p.bar;
  int ep = 0;

  float* keysT   = p.ws;
  float* valuesT = keysT + B * S * H;
  float* emb     = valuesT + B * S * H;
  float* h       = emb + B * H;
  float* c       = h + L * B * H;
  float* hmid    = c + L * B * H;
  float* cat     = hmid + L * B * H;
  float* q       = cat + L * B * 1024;
  float* logits  = q + L * B * H;      // reserved (fallback layout compat)
  float* slog    = logits + B * V;

  // ---- phase A: keys/values + state init ----
  {
    float* ch = smem;                  // 64*52
    float* wk = smem + 64 * 52;        // 49*52
    float* wv = wk + 49 * 52;
    int b = blk >> 3, dt = blk & 7;
    for (int i = tid; i < 49 * 49; i += NT) {
      int s = i / 49, j = i % 49;
      wk[s * 52 + j] = p.Wk[i]; wv[s * 52 + j] = p.Wv[i];
    }
    for (int i = tid; i < 64 * 49; i += NT) {
      int d = i / 49, j = i % 49;
      ch[d * 52 + j] = p.chan[((size_t)b * 512 + dt * 64 + d) * S + j];
    }
    __syncthreads();
    int dl = tid >> 3, sq = tid & 7;
    for (int s = sq; s < S; s += 8) {
      float ak = p.bk[s], av = p.bv[s];
      for (int j = 0; j < 49; ++j) {
        float cv = ch[dl * 52 + j];
        ak += cv * wk[s * 52 + j];
        av += cv * wv[s * 52 + j];
      }
      int d = dt * 64 + dl;
      keysT[((size_t)b * S + s) * H + d] = tanhf(ak);
      valuesT[((size_t)b * S + s) * H + d] = tanhf(av);
    }
    int idx = blk * NT + tid;
    if (idx < L * B * H) {
      float pv = p.pooled[idx & (B * H - 1)];
      h[idx] = pv; c[idx] = pv;
      if (idx < B * H) emb[idx] = p.embed[(size_t)p.sos[0] * H + (idx & (H - 1))];
    }
  }
  gsync(bar, ++ep, blk);

  // ---- phase B: proj of <SOS> embedding -> slog[0] ----
  proj_do(emb, slog, p.projW, p.projb, smem, blk, tid);
  gsync(bar, ++ep, blk);

  // ---- main T-loop ----
#pragma unroll 1
  for (int t = 0; t < T - 1; ++t) {
    lstm_do(emb, h, c, p.Wih, p.Whh, p.bih, p.bhh, hmid, smem, blk, tid);
    gsync(bar, ++ep, blk);
    lstm_do(hmid, h + B * H, c + B * H, p.Wih + 4 * H * H, p.Whh + 4 * H * H,
            p.bih + 4 * H, p.bhh + 4 * H, hmid + B * H, smem, blk, tid);
    gsync(bar, ++ep, blk);
    proj_do(hmid + B * H, slog + (size_t)(t + 1) * B * V, p.projW, p.projb,
            smem, blk, tid);
    if (t < T - 2 && blk >= 57 && blk < 89)
      q_do(hmid, p.Wq, p.bq, q, smem, blk - 57, tid);
    gsync(bar, ++ep, blk);
    if (t < T - 2) {   // last step: q/sattn/argmax/hatt outputs are dead
      if (blk < 64)
        sattn_do(q, keysT, valuesT, hmid, cat, smem, blk, tid);
      else if (blk < 96)
        argmax_do(slog + (size_t)(t + 1) * B * V, p.embed, emb, smem, blk - 64, tid);
      gsync(bar, ++ep, blk);
      if (blk < 64) hatt_do(cat, p.hattW, p.hattb, h, smem, blk, tid);
      gsync(bar, ++ep, blk);
    }
  }

  // ---- finalize: slog[t][b*V+v] -> out[b][v][t] ----
  for (int i = blk * NT + tid; i < B * V; i += NB * NT) {
    float vals[T];
#pragma unroll
    for (int t = 0; t < T; ++t) vals[t] = slog[(size_t)t * (B * V) + i];
#pragma unroll
    for (int t = 0; t < T; t += 4)
      *(float4*)&p.out[(size_t)i * T + t] =
          make_float4(vals[t], vals[t + 1], vals[t + 2], vals[t + 3]);
  }
}

// ===================== fallback: proven multi-kernel path =================

__global__ __launch_bounds__(256) void kv_kernel(
    const float* __restrict__ chan,
    const float* __restrict__ Wk, const float* __restrict__ bk,
    const float* __restrict__ Wv, const float* __restrict__ bv,
    float* __restrict__ keysT, float* __restrict__ valuesT) {
  __shared__ float ch[64][52];
  __shared__ float wk[49][52], wv[49][52];
  int b = blockIdx.x >> 3, dt = blockIdx.x & 7;
  int tid = threadIdx.x;
  for (int i = tid; i < 49 * 49; i += 256) {
    int s = i / 49, j = i % 49;
    wk[s][j] = Wk[i]; wv[s][j] = Wv[i];
  }
  for (int i = tid; i < 64 * 49; i += 256) {
    int d = i / 49, j = i % 49;
    ch[d][j] = chan[((size_t)b * 512 + dt * 64 + d) * S + j];
  }
  __syncthreads();
  int dl = tid >> 2, sq = tid & 3;
  for (int s = sq; s < S; s += 4) {
    float ak = bk[s], av = bv[s];
    for (int j = 0; j < 49; ++j) {
      float cv = ch[dl][j];
      ak += cv * wk[s][j];
      av += cv * wv[s][j];
    }
    int d = dt * 64 + dl;
    keysT[((size_t)b * S + s) * H + d] = tanhf(ak);
    valuesT[((size_t)b * S + s) * H + d] = tanhf(av);
  }
}

__global__ void init_kernel(const float* __restrict__ pooled,
                            const float* __restrict__ embed,
                            const int* __restrict__ sos,
                            float* __restrict__ emb, float* __restrict__ h,
                            float* __restrict__ c) {
  int idx = blockIdx.x * 256 + threadIdx.x;
  float p = pooled[idx & (B * H - 1)];
  h[idx] = p;
  c[idx] = p;
  if (idx < B * H) emb[idx] = embed[sos[0] * H + (idx & (H - 1))];
}

__global__ __launch_bounds__(256) void lstm_kernel(
    const float* __restrict__ x, const float* __restrict__ hprev,
    const float* __restrict__ cprev,
    const float* __restrict__ Wih, const float* __restrict__ Whh,
    const float* __restrict__ bih, const float* __restrict__ bhh,
    float* __restrict__ hout, float* __restrict__ cout) {
  __shared__ __align__(16) float smem[32 * 512];
  int tid = threadIdx.x;
  int hi = blockIdx.x;
  int ko = tid & 15, rr = (tid >> 4) & 3, bh = tid >> 6;
  {
    const float4* xg = (const float4*)x;
    float4* s4 = (float4*)smem;
    for (int i = tid; i < 4096; i += 256) s4[i] = xg[i];
  }
  __syncthreads();
  float acc[8];
#pragma unroll
  for (int j = 0; j < 8; ++j) acc[j] = 0.f;
  {
    const float* wrow = Wih + ((size_t)rr * H + hi) * H;
    float4 w[8];
#pragma unroll
    for (int kk = 0; kk < 8; ++kk) w[kk] = *(const float4*)&wrow[kk * 64 + ko * 4];
#pragma unroll
    for (int j = 0; j < 8; ++j) {
      const float* xb = smem + (bh * 8 + j) * 512;
#pragma unroll
      for (int kk = 0; kk < 8; ++kk)
        acc[j] += dot4(*(const float4*)&xb[kk * 64 + ko * 4], w[kk]);
    }
  }
  __syncthreads();
  {
    const float4* hg = (const float4*)hprev;
    float4* s4 = (float4*)smem;
    for (int i = tid; i < 4096; i += 256) s4[i] = hg[i];
  }
  __syncthreads();
  {
    const float* wrow = Whh + ((size_t)rr * H + hi) * H;
    float4 w[8];
#pragma unroll
    for (int kk = 0; kk < 8; ++kk) w[kk] = *(const float4*)&wrow[kk * 64 + ko * 4];
#pragma unroll
    for (int j = 0; j < 8; ++j) {
      const float* xb = smem + (bh * 8 + j) * 512;
#pragma unroll
      for (int kk = 0; kk < 8; ++kk)
        acc[j] += dot4(*(const float4*)&xb[kk * 64 + ko * 4], w[kk]);
    }
  }
  __syncthreads();
#pragma unroll
  for (int j = 0; j < 8; ++j) {
    acc[j] += __shfl_xor(acc[j], 1);
    acc[j] += __shfl_xor(acc[j], 2);
    acc[j] += __shfl_xor(acc[j], 4);
    acc[j] += __shfl_xor(acc[j], 8);
  }
  float* gbuf = smem;
  if (ko == 0) {
    float bias = bih[rr * H + hi] + bhh[rr * H + hi];
#pragma unroll
    for (int j = 0; j < 8; ++j) gbuf[rr * 32 + bh * 8 + j] = acc[j] + bias;
  }
  __syncthreads();
  if (tid < 32) {
    int b = tid;
    float gi = gbuf[b], gf = gbuf[32 + b], gg = gbuf[64 + b], go = gbuf[96 + b];
    float c2 = sigf(gf) * cprev[b * H + hi] + sigf(gi) * tanhf(gg);
    hout[b * H + hi] = sigf(go) * tanhf(c2);
    cout[b * H + hi] = c2;
  }
}

__global__ __launch_bounds__(256) void projq_kernel(
    const float* __restrict__ xin,
    const float* __restrict__ projW, const float* __restrict__ projb,
    float* __restrict__ logits, float* __restrict__ ocol, int direct, int tcol,
    const float* __restrict__ hmid_all, const float* __restrict__ Wq,
    const float* __restrict__ bq, float* __restrict__ q) {
  __shared__ __align__(16) float xs[32 * 512];
  int blk = blockIdx.x, tid = threadIdx.x;
  int ko = tid & 15, vl = tid >> 4;
  if (blk < 625) {
    {
      const float4* xg = (const float4*)xin;
      float4* s4 = (float4*)xs;
      for (int i = tid; i < 4096; i += 256) s4[i] = xg[i];
    }
    __syncthreads();
    int v = blk * 16 + vl;
    const float* wrow = projW + (size_t)v * H;
    float4 w[8];
#pragma unroll
    for (int kk = 0; kk < 8; ++kk) w[kk] = *(const float4*)&wrow[kk * 64 + ko * 4];
    float acc[32];
#pragma unroll
    for (int b = 0; b < 32; ++b) acc[b] = 0.f;
    for (int b = 0; b < 32; ++b) {
      const float* xb = xs + b * 512;
#pragma unroll
      for (int kk = 0; kk < 8; ++kk)
        acc[b] += dot4(*(const float4*)&xb[kk * 64 + ko * 4], w[kk]);
    }
#pragma unroll
    for (int b = 0; b < 32; ++b) {
      acc[b] += __shfl_xor(acc[b], 1);
      acc[b] += __shfl_xor(acc[b], 2);
      acc[b] += __shfl_xor(acc[b], 4);
      acc[b] += __shfl_xor(acc[b], 8);
    }
    if (ko == 0) {
      float bias = projb[v];
      for (int b = 0; b < 32; ++b) {
        float r = acc[b] + bias;
        logits[b * V + v] = r;
        if (direct) ocol[((size_t)b * V + v) * T + tcol] = r;
        else        ocol[b * V + v] = r;
      }
    }
  } else {
    int b2 = blk - 625;
    int lg = b2 & 1, jg = b2 >> 1;
    {
      const float4* xg = (const float4*)(hmid_all + lg * 32 * H);
      float4* s4 = (float4*)xs;
      for (int i = tid; i < 4096; i += 256) s4[i] = xg[i];
    }
    __syncthreads();
    int j = jg * 16 + vl;
    const float* wrow = Wq + (size_t)j * H;
    float4 w[8];
#pragma unroll
    for (int kk = 0; kk < 8; ++kk) w[kk] = *(const float4*)&wrow[kk * 64 + ko * 4];
    float acc[32];
#pragma unroll
    for (int b = 0; b < 32; ++b) acc[b] = 0.f;
    for (int b = 0; b < 32; ++b) {
      const float* xb = xs + b * 512;
#pragma unroll
      for (int kk = 0; kk < 8; ++kk)
        acc[b] += dot4(*(const float4*)&xb[kk * 64 + ko * 4], w[kk]);
    }
#pragma unroll
    for (int b = 0; b < 32; ++b) {
      acc[b] += __shfl_xor(acc[b], 1);
      acc[b] += __shfl_xor(acc[b], 2);
      acc[b] += __shfl_xor(acc[b], 4);
      acc[b] += __shfl_xor(acc[b], 8);
    }
    if (ko == 0) {
      float bias = bq[j];
      for (int b = 0; b < 32; ++b)
        q[(lg * 32 + b) * H + j] = tanhf(acc[b] + bias);
    }
  }
}

__global__ __launch_bounds__(256) void sattn_kernel(
    const float* __restrict__ q, const float* __restrict__ keysT,
    const float* __restrict__ valuesT, const float* __restrict__ hmid,
    float* __restrict__ cat) {
  __shared__ __align__(16) float qv[528];
  __shared__ float scl[64];
  __shared__ float wts[64];
  int lb = blockIdx.x, tid = threadIdx.x;
  int b = lb & 31;
  {
    int c0 = tid, c1 = tid + 256;
    qv[(c0 >> 7) * 132 + (c0 & 127)] = q[lb * H + c0];
    qv[(c1 >> 7) * 132 + (c1 & 127)] = q[lb * H + c1];
  }
  __syncthreads();
  int kq = tid & 3, sl = tid >> 2;
  float acc = 0.f;
  if (sl < S) {
    const float* kr = keysT + ((size_t)b * S + sl) * H + kq * 128;
    const float* qr = &qv[kq * 132];
    for (int k = 0; k < 128; k += 4)
      acc += dot4(*(const float4*)&qr[k], *(const float4*)&kr[k]);
  }
  acc += __shfl_xor(acc, 1);
  acc += __shfl_xor(acc, 2);
  if (kq == 0 && sl < S) scl[sl] = acc * (1.0f / 7.0f);
  __syncthreads();
  if (tid < 64) {
    float sc = (tid < S) ? scl[tid] : -3.4e38f;
    float m = sc;
    for (int o = 32; o > 0; o >>= 1) m = fmaxf(m, __shfl_xor(m, o));
    float e = (tid < S) ? expf(sc - m) : 0.f;
    float sum = e;
    for (int o = 32; o > 0; o >>= 1) sum += __shfl_xor(sum, o);
    if (tid < S) wts[tid] = e / sum;
  }
  __syncthreads();
  float acc0 = 0.f, acc1 = 0.f;
  for (int s = 0; s < S; ++s) {
    float w = wts[s];
    const float* vr = valuesT + ((size_t)b * S + s) * H;
    acc0 += w * vr[tid];
    acc1 += w * vr[tid + 256];
  }
  cat[lb * 1024 + tid] = acc0;
  cat[lb * 1024 + tid + 256] = acc1;
  cat[lb * 1024 + 512 + tid] = hmid[lb * H + tid];
  cat[lb * 1024 + 768 + tid] = hmid[lb * H + tid + 256];
}

__global__ __launch_bounds__(256) void hattarg_kernel(
    const float* __restrict__ cat, const float* __restrict__ hattW,
    const float* __restrict__ hattb, float* __restrict__ h,
    const float* __restrict__ logits, const float* __restrict__ embed,
    float* __restrict__ emb) {
  __shared__ __align__(16) float smem[16 * 1024];
  int blk = blockIdx.x, tid = threadIdx.x;
  if (blk < 128) {
    int lbg = blk & 3, jg = blk >> 2;
    {
      const float4* cg2 = (const float4*)(cat + lbg * 16 * 1024);
      float4* s4 = (float4*)smem;
      for (int i = tid; i < 4096; i += 256) s4[i] = cg2[i];
    }
    __syncthreads();
    int ko = tid & 15, jl = tid >> 4;
    int j = jg * 16 + jl;
    const float* wrow = hattW + (size_t)j * 1024;
    float4 w[16];
#pragma unroll
    for (int kk = 0; kk < 16; ++kk) w[kk] = *(const float4*)&wrow[kk * 64 + ko * 4];
    float acc[16];
#pragma unroll
    for (int lb = 0; lb < 16; ++lb) acc[lb] = 0.f;
    for (int lb = 0; lb < 16; ++lb) {
      const float* cb = smem + lb * 1024;
#pragma unroll
      for (int kk = 0; kk < 16; ++kk)
        acc[lb] += dot4(*(const float4*)&cb[kk * 64 + ko * 4], w[kk]);
    }
#pragma unroll
    for (int lb = 0; lb < 16; ++lb) {
      acc[lb] += __shfl_xor(acc[lb], 1);
      acc[lb] += __shfl_xor(acc[lb], 2);
      acc[lb] += __shfl_xor(acc[lb], 4);
      acc[lb] += __shfl_xor(acc[lb], 8);
    }
    if (ko == 0) {
      float bias = hattb[j];
      for (int lb = 0; lb < 16; ++lb)
        h[(lbg * 16 + lb) * H + j] = tanhf(acc[lb] + bias);
    }
  } else {
    int b = blk - 128;
    float* sv = smem;
    int* si = (int*)(smem + 256);
    float best = -3.4e38f;
    int bi = 0x7fffffff;
    for (int it = 0; it < 10; ++it) {
      int v0 = it * 1024 + tid * 4;
      if (v0 < V) {
        float4 lv = *(const float4*)&logits[b * V + v0];
        if (lv.x > best) { best = lv.x; bi = v0; }
        if (lv.y > best) { best = lv.y; bi = v0 + 1; }
        if (lv.z > best) { best = lv.z; bi = v0 + 2; }
        if (lv.w > best) { best = lv.w; bi = v0 + 3; }
      }
    }
    sv[tid] = best; si[tid] = bi;
    __syncthreads();
    for (int st = 128; st > 0; st >>= 1) {
      if (tid < st) {
        float ov = sv[tid + st]; int oi = si[tid + st];
        if (ov > sv[tid] || (ov == sv[tid] && oi < si[tid])) { sv[tid] = ov; si[tid] = oi; }
      }
      __syncthreads();
    }
    int idx = si[0];
    for (int i = tid; i < H; i += 256) emb[b * H + i] = embed[(size_t)idx * H + i];
  }
}

__global__ __launch_bounds__(256) void finalize_kernel(
    const float* __restrict__ slog, float* __restrict__ outp) {
  int idx = blockIdx.x * 256 + threadIdx.x;
  float vals[T];
#pragma unroll
  for (int t = 0; t < T; ++t) vals[t] = slog[(size_t)t * (B * V) + idx];
#pragma unroll
  for (int t = 0; t < T; t += 4)
    *(float4*)&outp[(size_t)idx * T + t] =
        make_float4(vals[t], vals[t + 1], vals[t + 2], vals[t + 3]);
}

}  // namespace

extern "C" void kernel_launch(void* const* d_in, const int* in_sizes, int n_in,
                              void* d_out, int out_size, void* d_ws, size_t ws_size,
                              hipStream_t stream) {
  (void)in_sizes; (void)n_in; (void)out_size;
  const float* chan   = (const float*)d_in[0];
  const float* pooled = (const float*)d_in[1];
  const float* embed  = (const float*)d_in[2];
  const float* Wq     = (const float*)d_in[3];
  const float* bq     = (const float*)d_in[4];
  const float* Wk     = (const float*)d_in[5];
  const float* bk     = (const float*)d_in[6];
  const float* Wv     = (const float*)d_in[7];
  const float* bv     = (const float*)d_in[8];
  const float* Wih    = (const float*)d_in[9];
  const float* Whh    = (const float*)d_in[10];
  const float* bih    = (const float*)d_in[11];
  const float* bhh    = (const float*)d_in[12];
  const float* projW  = (const float*)d_in[13];
  const float* projb  = (const float*)d_in[14];
  const float* hattW  = (const float*)d_in[15];
  const float* hattb  = (const float*)d_in[16];
  const int*   sos    = (const int*)d_in[17];

  float* out = (float*)d_out;
  int*   bar = (int*)d_ws;                 // barrier region (first 2 KB)
  float* ws  = (float*)d_ws + 512;         // data region

  float* keysT   = ws;
  float* valuesT = keysT + B * S * 512;
  float* emb     = valuesT + B * S * 512;
  float* h       = emb + B * H;
  float* c       = h + L * B * H;
  float* hmid    = c + L * B * H;
  float* cat     = hmid + L * B * H;
  float* q       = cat + L * B * 1024;
  float* logits  = q + L * B * H;
  float* slog    = logits + B * V;

  size_t need_floats = 512 + (size_t)(slog - ws) + (size_t)T * B * V;
  bool fits = ws_size >= need_floats * sizeof(float);

  if (fits) {
    (void)hipMemsetAsync(d_ws, 0, 2048, stream);  // zero barrier counters
    KParams p = {chan, pooled, embed, Wq, bq, Wk, bk, Wv, bv,
                 Wih, Whh, bih, bhh, projW, projb, hattW, hattb,
                 sos, out, ws, bar};
    persist<<<NB, NT, 0, stream>>>(p);
    return;
  }

  // -------- fallback: previous verified multi-kernel path --------
  size_t base_floats = (size_t)(slog - ws) + 512;
  bool staged = ws_size >= (base_floats + (size_t)T * B * V) * sizeof(float);

  kv_kernel<<<256, 256, 0, stream>>>(chan, Wk, bk, Wv, bv, keysT, valuesT);
  init_kernel<<<(L * B * H) / 256, 256, 0, stream>>>(pooled, embed, sos, emb, h, c);
  {
    float* oc = staged ? slog : out;
    projq_kernel<<<625, 256, 0, stream>>>(emb, projW, projb, logits, oc,
                                          staged ? 0 : 1, 0,
                                          hmid, Wq, bq, q);
  }
  for (int t = 0; t < T - 1; ++t) {
    float* oc = staged ? (slog + (size_t)(t + 1) * B * V) : out;
    lstm_kernel<<<512, 256, 0, stream>>>(emb, h, c, Wih, Whh, bih, bhh, hmid, c);
    lstm_kernel<<<512, 256, 0, stream>>>(hmid, h + B * H, c + B * H,
                                         Wih + 4 * H * H, Whh + 4 * H * H,
                                         bih + 4 * H, bhh + 4 * H,
                                         hmid + B * H, c + B * H);
    projq_kernel<<<689, 256, 0, stream>>>(hmid + B * H, projW, projb, logits, oc,
                                          staged ? 0 : 1, t + 1,
                                          hmid, Wq, bq, q);
    sattn_kernel<<<L * B, 256, 0, stream>>>(q, keysT, valuesT, hmid, cat);
    hattarg_kernel<<<160, 256, 0, stream>>>(cat, hattW, hattb, h,
                                            logits, embed, emb);
  }
  if (staged) finalize_kernel<<<(B * V) / 256, 256, 0, stream>>>(slog, out);
}

// Round 5
// 4003.816 us; speedup vs baseline: 1.5038x; 1.1364x over previous
//
#include <hip/hip_runtime.h>

namespace {

constexpr int B = 32, H = 512, L = 2, T = 20, V = 10000, S = 49;
constexpr int NB = 256, NT = 512;   // persistent grid: 1 block/CU, all resident

__device__ __forceinline__ float sigf(float x) { return 1.0f / (1.0f + expf(-x)); }
__device__ __forceinline__ float dot4(float4 a, float4 b) {
  return a.x*b.x + a.y*b.y + a.z*b.z + a.w*b.w;
}

// Agent-scope (uncached / coherence-point) accessors for cross-block data.
__device__ __forceinline__ float cohf(const float* p) {
  return __hip_atomic_load(p, __ATOMIC_RELAXED, __HIP_MEMORY_SCOPE_AGENT);
}
__device__ __forceinline__ void cohst(float* p, float v) {
  __hip_atomic_store(p, v, __ATOMIC_RELAXED, __HIP_MEMORY_SCOPE_AGENT);
}
__device__ __forceinline__ unsigned long long cohu8(const unsigned long long* p) {
  return __hip_atomic_load(p, __ATOMIC_RELAXED, __HIP_MEMORY_SCOPE_AGENT);
}

struct KParams {
  const float *chan, *pooled, *embed, *Wq, *bq, *Wk, *bk, *Wv, *bv,
              *Wih, *Whh, *bih, *bhh, *projW, *projb, *hattW, *hattb;
  const int* sos;
  float* out;
  float* ws;    // data region
  int* bar;     // barrier region: 16 leaves @ stride 16 ints, root @ [256]
};

// ---- grid barrier: NO FENCES. __syncthreads() drains vmcnt(0) (stores   ----
// ---- acked at coherence point) before the arrival add. Data plane is    ----
// ---- uncached-atomic, so no cache invalidation is needed for acquire.   ----
__device__ __forceinline__ void gsync(int* bar, int ep, int blk) {
  __syncthreads();   // all this block's stores retired (vmcnt 0) before arrival
  if (threadIdx.x == 0) {
    int g = blk & 15;
    int r = __hip_atomic_fetch_add(&bar[g * 16], 1,
                                   __ATOMIC_RELAXED, __HIP_MEMORY_SCOPE_AGENT);
    if (r == ep * 16 - 1)   // last of this leaf's 16 blocks this epoch
      __hip_atomic_fetch_add(&bar[256], 1,
                             __ATOMIC_RELAXED, __HIP_MEMORY_SCOPE_AGENT);
    unsigned spins = 0;
    while (__hip_atomic_load(&bar[256], __ATOMIC_RELAXED,
                             __HIP_MEMORY_SCOPE_AGENT) < ep * 16) {
      __builtin_amdgcn_s_sleep(8);
      if (++spins > (1u << 20)) break;   // bail: fail verification, never hang
    }
  }
  __syncthreads();
}

// ===================== persistent-kernel phase bodies =====================

// Uncached 64 KB stage (8 B granules): cross-phase activations only.
__device__ __forceinline__ void stage64k(const float* __restrict__ src,
                                         float* smem, int tid) {
  const unsigned long long* g = (const unsigned long long*)src;
  unsigned long long* s8 = (unsigned long long*)smem;
  for (int i = tid; i < 8192; i += NT) s8[i] = cohu8(g + i);
}

// LSTM: each block owns 2 hi rows; 256-thread-half mapping identical to the
// proven lstm_kernel (ko16 x rr4 x bh4, 8 batches) -> identical numerics.
__device__ __forceinline__ void lstm_do(
    const float* __restrict__ x, const float* __restrict__ hp,
    float* __restrict__ cp, const float* __restrict__ Wih,
    const float* __restrict__ Whh, const float* __restrict__ bih,
    const float* __restrict__ bhh, float* __restrict__ ho,
    float* smem, int blk, int tid) {
  int tl = tid & 255, hh = tid >> 8;
  int ko = tl & 15, rr = (tl >> 4) & 3, bh = tl >> 6;
  int hi = blk * 2 + hh;
  stage64k(x, smem, tid);
  __syncthreads();
  float acc[8];
#pragma unroll
  for (int j = 0; j < 8; ++j) acc[j] = 0.f;
  {
    const float* wrow = Wih + ((size_t)rr * H + hi) * H;   // normal: L2-warm
    float4 w[8];
#pragma unroll
    for (int kk = 0; kk < 8; ++kk) w[kk] = *(const float4*)&wrow[kk * 64 + ko * 4];
#pragma unroll
    for (int j = 0; j < 8; ++j) {
      const float* xb = smem + (bh * 8 + j) * 512;
#pragma unroll
      for (int kk = 0; kk < 8; ++kk)
        acc[j] += dot4(*(const float4*)&xb[kk * 64 + ko * 4], w[kk]);
    }
  }
  __syncthreads();
  stage64k(hp, smem, tid);
  __syncthreads();
  {
    const float* wrow = Whh + ((size_t)rr * H + hi) * H;
    float4 w[8];
#pragma unroll
    for (int kk = 0; kk < 8; ++kk) w[kk] = *(const float4*)&wrow[kk * 64 + ko * 4];
#pragma unroll
    for (int j = 0; j < 8; ++j) {
      const float* xb = smem + (bh * 8 + j) * 512;
#pragma unroll
      for (int kk = 0; kk < 8; ++kk)
        acc[j] += dot4(*(const float4*)&xb[kk * 64 + ko * 4], w[kk]);
    }
  }
  __syncthreads();   // all LDS reads done before gbuf overwrite
#pragma unroll
  for (int j = 0; j < 8; ++j) {
    acc[j] += __shfl_xor(acc[j], 1);
    acc[j] += __shfl_xor(acc[j], 2);
    acc[j] += __shfl_xor(acc[j], 4);
    acc[j] += __shfl_xor(acc[j], 8);
  }
  float* gbuf = smem;   // 256 floats reused
  if (ko == 0) {
    float bias = bih[rr * H + hi] + bhh[rr * H + hi];
#pragma unroll
    for (int j = 0; j < 8; ++j) gbuf[hh * 128 + rr * 32 + bh * 8 + j] = acc[j] + bias;
  }
  __syncthreads();
  if (tid < 64) {
    int hs = tid >> 5, b = tid & 31;
    int hi2 = blk * 2 + hs;
    const float* gb = gbuf + hs * 128;
    float gi = gb[b], gf = gb[32 + b], gg = gb[64 + b], go = gb[96 + b];
    // c is block-private across the whole loop: normal load/store (own L2).
    float c2 = sigf(gf) * cp[b * H + hi2] + sigf(gi) * tanhf(gg);
    cohst(&ho[b * H + hi2], sigf(go) * tanhf(c2));   // cross-block: uncached
    cp[b * H + hi2] = c2;
  }
}

// proj: 313 chunks of 32 v-rows over 256 blocks (blocks 0..56 do two).
__device__ __forceinline__ void proj_do(
    const float* __restrict__ x, float* __restrict__ dst,
    const float* __restrict__ projW, const float* __restrict__ projb,
    float* smem, int blk, int tid) {
  stage64k(x, smem, tid);
  __syncthreads();
  int ko = tid & 15, vl = tid >> 4;   // vl 0..31
  for (int chunk = blk; chunk < 313; chunk += NB) {
    int v = chunk * 32 + vl;
    if (v < V) {
      const float* wrow = projW + (size_t)v * H;   // normal: L2-warm, fixed blk->rows
      float4 w[8];
#pragma unroll
      for (int kk = 0; kk < 8; ++kk) w[kk] = *(const float4*)&wrow[kk * 64 + ko * 4];
      float acc[32];
#pragma unroll
      for (int b = 0; b < 32; ++b) acc[b] = 0.f;
      for (int b = 0; b < 32; ++b) {
        const float* xb = smem + b * 512;
#pragma unroll
        for (int kk = 0; kk < 8; ++kk)
          acc[b] += dot4(*(const float4*)&xb[kk * 64 + ko * 4], w[kk]);
      }
#pragma unroll
      for (int b = 0; b < 32; ++b) {
        acc[b] += __shfl_xor(acc[b], 1);
        acc[b] += __shfl_xor(acc[b], 2);
        acc[b] += __shfl_xor(acc[b], 4);
        acc[b] += __shfl_xor(acc[b], 8);
      }
      if (ko == 0) {
        float bias = projb[v];
        for (int b = 0; b < 32; ++b) cohst(&dst[(size_t)b * V + v], acc[b] + bias);
      }
    }
  }
}

// q: 32 units (2 lg x 16 jg of 32 j); runs on blocks 57..88 after their proj chunk.
__device__ __forceinline__ void q_do(
    const float* __restrict__ hmid, const float* __restrict__ Wq,
    const float* __restrict__ bq, float* __restrict__ q,
    float* smem, int u, int tid) {
  int lg = u & 1, jg = u >> 1;
  __syncthreads();                       // done reading proj's staged x
  stage64k(hmid + (size_t)lg * B * H, smem, tid);
  __syncthreads();
  int ko = tid & 15, jl = tid >> 4;
  int j = jg * 32 + jl;
  const float* wrow = Wq + (size_t)j * H;
  float4 w[8];
#pragma unroll
  for (int kk = 0; kk < 8; ++kk) w[kk] = *(const float4*)&wrow[kk * 64 + ko * 4];
  float acc[32];
#pragma unroll
  for (int b = 0; b < 32; ++b) acc[b] = 0.f;
  for (int b = 0; b < 32; ++b) {
    const float* xb = smem + b * 512;
#pragma unroll
    for (int kk = 0; kk < 8; ++kk)
      acc[b] += dot4(*(const float4*)&xb[kk * 64 + ko * 4], w[kk]);
  }
#pragma unroll
  for (int b = 0; b < 32; ++b) {
    acc[b] += __shfl_xor(acc[b], 1);
    acc[b] += __shfl_xor(acc[b], 2);
    acc[b] += __shfl_xor(acc[b], 4);
    acc[b] += __shfl_xor(acc[b], 8);
  }
  if (ko == 0) {
    float bias = bq[j];
    for (int b = 0; b < 32; ++b)
      cohst(&q[(size_t)(lg * 32 + b) * H + j], tanhf(acc[b] + bias));
  }
}

// sattn: one block per lb (blocks 0..63).
__device__ __forceinline__ void sattn_do(
    const float* __restrict__ q, const float* __restrict__ keysT,
    const float* __restrict__ valuesT, const float* __restrict__ hmid,
    float* __restrict__ cat, float* smem, int lb, int tid) {
  float* qv = smem;            // 4 chunks of 132 (128+4 skew)
  float* scl = smem + 544;
  float* wts = smem + 608;
  int b = lb & 31;
  qv[(tid >> 7) * 132 + (tid & 127)] = cohf(&q[(size_t)lb * H + tid]);
  __syncthreads();
  int kq = tid & 3, sl = tid >> 2;
  float acc = 0.f;
  if (sl < S) {
    const float* kr = keysT + ((size_t)b * S + sl) * H + kq * 128;  // normal: L2-warm
    const float* qr = &qv[kq * 132];
    for (int k = 0; k < 128; k += 4)
      acc += dot4(*(const float4*)&qr[k], *(const float4*)&kr[k]);
  }
  acc += __shfl_xor(acc, 1);
  acc += __shfl_xor(acc, 2);
  if (kq == 0 && sl < S) scl[sl] = acc * (1.0f / 7.0f);
  __syncthreads();
  if (tid < 64) {
    float sc = (tid < S) ? scl[tid] : -3.4e38f;
    float m = sc;
    for (int o = 32; o > 0; o >>= 1) m = fmaxf(m, __shfl_xor(m, o));
    float e = (tid < S) ? expf(sc - m) : 0.f;
    float sum = e;
    for (int o = 32; o > 0; o >>= 1) sum += __shfl_xor(sum, o);
    if (tid < S) wts[tid] = e / sum;
  }
  __syncthreads();
  float a0 = 0.f;
  for (int s = 0; s < S; ++s)
    a0 += wts[s] * valuesT[((size_t)b * S + s) * H + tid];   // normal: L2-warm
  cohst(&cat[(size_t)lb * 1024 + tid], a0);
  cohst(&cat[(size_t)lb * 1024 + 512 + tid], cohf(&hmid[(size_t)lb * H + tid]));
}

// argmax+embed: one block per batch (blocks 64..95). Lowest-index-on-tie.
// Reads slog via uncached loads (no L2 pollution; slog stored uncached).
__device__ __forceinline__ void argmax_do(
    const float* __restrict__ lgts, const float* __restrict__ embed,
    float* __restrict__ emb, float* smem, int b, int tid) {
  float* sv = smem;
  int* si = (int*)(smem + 512);
  float best = -3.4e38f;
  int bi = 0x7fffffff;
  for (int it = 0; it < 5; ++it) {
    int v0 = it * 2048 + tid * 4;
    if (v0 < V) {
      unsigned long long u0 = cohu8((const unsigned long long*)&lgts[(size_t)b * V + v0]);
      unsigned long long u1 = cohu8((const unsigned long long*)&lgts[(size_t)b * V + v0 + 2]);
      float x = __uint_as_float((unsigned)u0);
      float y = __uint_as_float((unsigned)(u0 >> 32));
      float z = __uint_as_float((unsigned)u1);
      float w = __uint_as_float((unsigned)(u1 >> 32));
      if (x > best) { best = x; bi = v0; }
      if (y > best) { best = y; bi = v0 + 1; }
      if (z > best) { best = z; bi = v0 + 2; }
      if (w > best) { best = w; bi = v0 + 3; }
    }
  }
  sv[tid] = best; si[tid] = bi;
  __syncthreads();
  for (int st = 256; st > 0; st >>= 1) {
    if (tid < st) {
      float ov = sv[tid + st]; int oi = si[tid + st];
      if (ov > sv[tid] || (ov == sv[tid] && oi < si[tid])) { sv[tid] = ov; si[tid] = oi; }
    }
    __syncthreads();
  }
  int idx = si[0];
  cohst(&emb[(size_t)b * H + tid], embed[(size_t)idx * H + tid]);
}

// hatt: blocks 0..63 (lbg4 x jg16, 32 j x 16 lb each).
__device__ __forceinline__ void hatt_do(
    const float* __restrict__ cat, const float* __restrict__ hattW,
    const float* __restrict__ hattb, float* __restrict__ h,
    float* smem, int blk, int tid) {
  int lbg = blk & 3, jg = blk >> 2;
  stage64k(cat + (size_t)lbg * 16 * 1024, smem, tid);
  __syncthreads();
  int ko = tid & 15, jl = tid >> 4;
  int j = jg * 32 + jl;
  const float* wrow = hattW + (size_t)j * 1024;   // normal: L2-warm
  float4 w[16];
#pragma unroll
  for (int kk = 0; kk < 16; ++kk) w[kk] = *(const float4*)&wrow[kk * 64 + ko * 4];
  float acc[16];
#pragma unroll
  for (int lb = 0; lb < 16; ++lb) acc[lb] = 0.f;
  for (int lb = 0; lb < 16; ++lb) {
    const float* cb = smem + lb * 1024;
#pragma unroll
    for (int kk = 0; kk < 16; ++kk)
      acc[lb] += dot4(*(const float4*)&cb[kk * 64 + ko * 4], w[kk]);
  }
#pragma unroll
  for (int lb = 0; lb < 16; ++lb) {
    acc[lb] += __shfl_xor(acc[lb], 1);
    acc[lb] += __shfl_xor(acc[lb], 2);
    acc[lb] += __shfl_xor(acc[lb], 4);
    acc[lb] += __shfl_xor(acc[lb], 8);
  }
  if (ko == 0) {
    float bias = hattb[j];
    for (int lb = 0; lb < 16; ++lb)
      cohst(&h[(size_t)(lbg * 16 + lb) * H + j], tanhf(acc[lb] + bias));
  }
}

// ===================== the persistent kernel (plain launch) ===============
__global__ __launch_bounds__(NT, 4) void persist(KParams p) {
  __shared__ __align__(16) float smem[16384];   // 64 KB
  const int blk = blockIdx.x, tid = threadIdx.x;
  int* bar = p.bar;
  int ep = 0;

  float* keysT   = p.ws;
  float* valuesT = keysT + B * S * H;
  float* emb     = valuesT + B * S * H;
  float* h       = emb + B * H;
  float* c       = h + L * B * H;
  float* hmid    = c + L * B * H;
  float* cat     = hmid + L * B * H;
  float* q       = cat + L * B * 1024;
  float* logits  = q + L * B * H;      // reserved (fallback layout compat)
  float* slog    = logits + B * V;

  // ---- phase A: keys/values + state init ----
  {
    float* ch = smem;                  // 64*52
    float* wk = smem + 64 * 52;        // 49*52
    float* wv = wk + 49 * 52;
    int b = blk >> 3, dt = blk & 7;
    for (int i = tid; i < 49 * 49; i += NT) {
      int s = i / 49, j = i % 49;
      wk[s * 52 + j] = p.Wk[i]; wv[s * 52 + j] = p.Wv[i];
    }
    for (int i = tid; i < 64 * 49; i += NT) {
      int d = i / 49, j = i % 49;
      ch[d * 52 + j] = p.chan[((size_t)b * 512 + dt * 64 + d) * S + j];
    }
    __syncthreads();
    int dl = tid >> 3, sq = tid & 7;
    for (int s = sq; s < S; s += 8) {
      float ak = p.bk[s], av = p.bv[s];
      for (int j = 0; j < 49; ++j) {
        float cv = ch[dl * 52 + j];
        ak += cv * wk[s * 52 + j];
        av += cv * wv[s * 52 + j];
      }
      int d = dt * 64 + dl;
      cohst(&keysT[((size_t)b * S + s) * H + d], tanhf(ak));
      cohst(&valuesT[((size_t)b * S + s) * H + d], tanhf(av));
    }
    int idx = blk * NT + tid;
    if (idx < L * B * H) {
      float pv = p.pooled[idx & (B * H - 1)];
      cohst(&h[idx], pv);
      cohst(&c[idx], pv);   // first owner read fetches fresh; then block-private
      if (idx < B * H)
        cohst(&emb[idx], p.embed[(size_t)p.sos[0] * H + (idx & (H - 1))]);
    }
  }
  gsync(bar, ++ep, blk);

  // ---- phase B: proj of <SOS> embedding -> slog[0] ----
  proj_do(emb, slog, p.projW, p.projb, smem, blk, tid);
  gsync(bar, ++ep, blk);

  // ---- main T-loop ----
#pragma unroll 1
  for (int t = 0; t < T - 1; ++t) {
    lstm_do(emb, h, c, p.Wih, p.Whh, p.bih, p.bhh, hmid, smem, blk, tid);
    gsync(bar, ++ep, blk);
    lstm_do(hmid, h + B * H, c + B * H, p.Wih + 4 * H * H, p.Whh + 4 * H * H,
            p.bih + 4 * H, p.bhh + 4 * H, hmid + B * H, smem, blk, tid);
    gsync(bar, ++ep, blk);
    proj_do(hmid + B * H, slog + (size_t)(t + 1) * B * V, p.projW, p.projb,
            smem, blk, tid);
    if (t < T - 2 && blk >= 57 && blk < 89)
      q_do(hmid, p.Wq, p.bq, q, smem, blk - 57, tid);
    gsync(bar, ++ep, blk);
    if (t < T - 2) {   // last step: q/sattn/argmax/hatt outputs are dead
      if (blk < 64)
        sattn_do(q, keysT, valuesT, hmid, cat, smem, blk, tid);
      else if (blk < 96)
        argmax_do(slog + (size_t)(t + 1) * B * V, p.embed, emb, smem, blk - 64, tid);
      gsync(bar, ++ep, blk);
      if (blk < 64) hatt_do(cat, p.hattW, p.hattb, h, smem, blk, tid);
      gsync(bar, ++ep, blk);
    }
  }

  // ---- finalize: slog[t][b*V+v] -> out[b][v][t] (slog immutable now) ----
  for (int i = blk * NT + tid; i < B * V; i += NB * NT) {
    float vals[T];
#pragma unroll
    for (int t = 0; t < T; ++t) vals[t] = cohf(&slog[(size_t)t * (B * V) + i]);
#pragma unroll
    for (int t = 0; t < T; t += 4)
      *(float4*)&p.out[(size_t)i * T + t] =
          make_float4(vals[t], vals[t + 1], vals[t + 2], vals[t + 3]);
  }
}

// ===================== fallback: proven multi-kernel path =================

__global__ __launch_bounds__(256) void kv_kernel(
    const float* __restrict__ chan,
    const float* __restrict__ Wk, const float* __restrict__ bk,
    const float* __restrict__ Wv, const float* __restrict__ bv,
    float* __restrict__ keysT, float* __restrict__ valuesT) {
  __shared__ float ch[64][52];
  __shared__ float wk[49][52], wv[49][52];
  int b = blockIdx.x >> 3, dt = blockIdx.x & 7;
  int tid = threadIdx.x;
  for (int i = tid; i < 49 * 49; i += 256) {
    int s = i / 49, j = i % 49;
    wk[s][j] = Wk[i]; wv[s][j] = Wv[i];
  }
  for (int i = tid; i < 64 * 49; i += 256) {
    int d = i / 49, j = i % 49;
    ch[d][j] = chan[((size_t)b * 512 + dt * 64 + d) * S + j];
  }
  __syncthreads();
  int dl = tid >> 2, sq = tid & 3;
  for (int s = sq; s < S; s += 4) {
    float ak = bk[s], av = bv[s];
    for (int j = 0; j < 49; ++j) {
      float cv = ch[dl][j];
      ak += cv * wk[s][j];
      av += cv * wv[s][j];
    }
    int d = dt * 64 + dl;
    keysT[((size_t)b * S + s) * H + d] = tanhf(ak);
    valuesT[((size_t)b * S + s) * H + d] = tanhf(av);
  }
}

__global__ void init_kernel(const float* __restrict__ pooled,
                            const float* __restrict__ embed,
                            const int* __restrict__ sos,
                            float* __restrict__ emb, float* __restrict__ h,
                            float* __restrict__ c) {
  int idx = blockIdx.x * 256 + threadIdx.x;
  float p = pooled[idx & (B * H - 1)];
  h[idx] = p;
  c[idx] = p;
  if (idx < B * H) emb[idx] = embed[sos[0] * H + (idx & (H - 1))];
}

__global__ __launch_bounds__(256) void lstm_kernel(
    const float* __restrict__ x, const float* __restrict__ hprev,
    const float* __restrict__ cprev,
    const float* __restrict__ Wih, const float* __restrict__ Whh,
    const float* __restrict__ bih, const float* __restrict__ bhh,
    float* __restrict__ hout, float* __restrict__ cout) {
  __shared__ __align__(16) float smem[32 * 512];
  int tid = threadIdx.x;
  int hi = blockIdx.x;
  int ko = tid & 15, rr = (tid >> 4) & 3, bh = tid >> 6;
  {
    const float4* xg = (const float4*)x;
    float4* s4 = (float4*)smem;
    for (int i = tid; i < 4096; i += 256) s4[i] = xg[i];
  }
  __syncthreads();
  float acc[8];
#pragma unroll
  for (int j = 0; j < 8; ++j) acc[j] = 0.f;
  {
    const float* wrow = Wih + ((size_t)rr * H + hi) * H;
    float4 w[8];
#pragma unroll
    for (int kk = 0; kk < 8; ++kk) w[kk] = *(const float4*)&wrow[kk * 64 + ko * 4];
#pragma unroll
    for (int j = 0; j < 8; ++j) {
      const float* xb = smem + (bh * 8 + j) * 512;
#pragma unroll
      for (int kk = 0; kk < 8; ++kk)
        acc[j] += dot4(*(const float4*)&xb[kk * 64 + ko * 4], w[kk]);
    }
  }
  __syncthreads();
  {
    const float4* hg = (const float4*)hprev;
    float4* s4 = (float4*)smem;
    for (int i = tid; i < 4096; i += 256) s4[i] = hg[i];
  }
  __syncthreads();
  {
    const float* wrow = Whh + ((size_t)rr * H + hi) * H;
    float4 w[8];
#pragma unroll
    for (int kk = 0; kk < 8; ++kk) w[kk] = *(const float4*)&wrow[kk * 64 + ko * 4];
#pragma unroll
    for (int j = 0; j < 8; ++j) {
      const float* xb = smem + (bh * 8 + j) * 512;
#pragma unroll
      for (int kk = 0; kk < 8; ++kk)
        acc[j] += dot4(*(const float4*)&xb[kk * 64 + ko * 4], w[kk]);
    }
  }
  __syncthreads();
#pragma unroll
  for (int j = 0; j < 8; ++j) {
    acc[j] += __shfl_xor(acc[j], 1);
    acc[j] += __shfl_xor(acc[j], 2);
    acc[j] += __shfl_xor(acc[j], 4);
    acc[j] += __shfl_xor(acc[j], 8);
  }
  float* gbuf = smem;
  if (ko == 0) {
    float bias = bih[rr * H + hi] + bhh[rr * H + hi];
#pragma unroll
    for (int j = 0; j < 8; ++j) gbuf[rr * 32 + bh * 8 + j] = acc[j] + bias;
  }
  __syncthreads();
  if (tid < 32) {
    int b = tid;
    float gi = gbuf[b], gf = gbuf[32 + b], gg = gbuf[64 + b], go = gbuf[96 + b];
    float c2 = sigf(gf) * cprev[b * H + hi] + sigf(gi) * tanhf(gg);
    hout[b * H + hi] = sigf(go) * tanhf(c2);
    cout[b * H + hi] = c2;
  }
}

__global__ __launch_bounds__(256) void projq_kernel(
    const float* __restrict__ xin,
    const float* __restrict__ projW, const float* __restrict__ projb,
    float* __restrict__ logits, float* __restrict__ ocol, int direct, int tcol,
    const float* __restrict__ hmid_all, const float* __restrict__ Wq,
    const float* __restrict__ bq, float* __restrict__ q) {
  __shared__ __align__(16) float xs[32 * 512];
  int blk = blockIdx.x, tid = threadIdx.x;
  int ko = tid & 15, vl = tid >> 4;
  if (blk < 625) {
    {
      const float4* xg = (const float4*)xin;
      float4* s4 = (float4*)xs;
      for (int i = tid; i < 4096; i += 256) s4[i] = xg[i];
    }
    __syncthreads();
    int v = blk * 16 + vl;
    const float* wrow = projW + (size_t)v * H;
    float4 w[8];
#pragma unroll
    for (int kk = 0; kk < 8; ++kk) w[kk] = *(const float4*)&wrow[kk * 64 + ko * 4];
    float acc[32];
#pragma unroll
    for (int b = 0; b < 32; ++b) acc[b] = 0.f;
    for (int b = 0; b < 32; ++b) {
      const float* xb = xs + b * 512;
#pragma unroll
      for (int kk = 0; kk < 8; ++kk)
        acc[b] += dot4(*(const float4*)&xb[kk * 64 + ko * 4], w[kk]);
    }
#pragma unroll
    for (int b = 0; b < 32; ++b) {
      acc[b] += __shfl_xor(acc[b], 1);
      acc[b] += __shfl_xor(acc[b], 2);
      acc[b] += __shfl_xor(acc[b], 4);
      acc[b] += __shfl_xor(acc[b], 8);
    }
    if (ko == 0) {
      float bias = projb[v];
      for (int b = 0; b < 32; ++b) {
        float r = acc[b] + bias;
        logits[b * V + v] = r;
        if (direct) ocol[((size_t)b * V + v) * T + tcol] = r;
        else        ocol[b * V + v] = r;
      }
    }
  } else {
    int b2 = blk - 625;
    int lg = b2 & 1, jg = b2 >> 1;
    {
      const float4* xg = (const float4*)(hmid_all + lg * 32 * H);
      float4* s4 = (float4*)xs;
      for (int i = tid; i < 4096; i += 256) s4[i] = xg[i];
    }
    __syncthreads();
    int j = jg * 16 + vl;
    const float* wrow = Wq + (size_t)j * H;
    float4 w[8];
#pragma unroll
    for (int kk = 0; kk < 8; ++kk) w[kk] = *(const float4*)&wrow[kk * 64 + ko * 4];
    float acc[32];
#pragma unroll
    for (int b = 0; b < 32; ++b) acc[b] = 0.f;
    for (int b = 0; b < 32; ++b) {
      const float* xb = xs + b * 512;
#pragma unroll
      for (int kk = 0; kk < 8; ++kk)
        acc[b] += dot4(*(const float4*)&xb[kk * 64 + ko * 4], w[kk]);
    }
#pragma unroll
    for (int b = 0; b < 32; ++b) {
      acc[b] += __shfl_xor(acc[b], 1);
      acc[b] += __shfl_xor(acc[b], 2);
      acc[b] += __shfl_xor(acc[b], 4);
      acc[b] += __shfl_xor(acc[b], 8);
    }
    if (ko == 0) {
      float bias = bq[j];
      for (int b = 0; b < 32; ++b)
        q[(lg * 32 + b) * H + j] = tanhf(acc[b] + bias);
    }
  }
}

__global__ __launch_bounds__(256) void sattn_kernel(
    const float* __restrict__ q, const float* __restrict__ keysT,
    const float* __restrict__ valuesT, const float* __restrict__ hmid,
    float* __restrict__ cat) {
  __shared__ __align__(16) float qv[528];
  __shared__ float scl[64];
  __shared__ float wts[64];
  int lb = blockIdx.x, tid = threadIdx.x;
  int b = lb & 31;
  {
    int c0 = tid, c1 = tid + 256;
    qv[(c0 >> 7) * 132 + (c0 & 127)] = q[lb * H + c0];
    qv[(c1 >> 7) * 132 + (c1 & 127)] = q[lb * H + c1];
  }
  __syncthreads();
  int kq = tid & 3, sl = tid >> 2;
  float acc = 0.f;
  if (sl < S) {
    const float* kr = keysT + ((size_t)b * S + sl) * H + kq * 128;
    const float* qr = &qv[kq * 132];
    for (int k = 0; k < 128; k += 4)
      acc += dot4(*(const float4*)&qr[k], *(const float4*)&kr[k]);
  }
  acc += __shfl_xor(acc, 1);
  acc += __shfl_xor(acc, 2);
  if (kq == 0 && sl < S) scl[sl] = acc * (1.0f / 7.0f);
  __syncthreads();
  if (tid < 64) {
    float sc = (tid < S) ? scl[tid] : -3.4e38f;
    float m = sc;
    for (int o = 32; o > 0; o >>= 1) m = fmaxf(m, __shfl_xor(m, o));
    float e = (tid < S) ? expf(sc - m) : 0.f;
    float sum = e;
    for (int o = 32; o > 0; o >>= 1) sum += __shfl_xor(sum, o);
    if (tid < S) wts[tid] = e / sum;
  }
  __syncthreads();
  float acc0 = 0.f, acc1 = 0.f;
  for (int s = 0; s < S; ++s) {
    float w = wts[s];
    const float* vr = valuesT + ((size_t)b * S + s) * H;
    acc0 += w * vr[tid];
    acc1 += w * vr[tid + 256];
  }
  cat[lb * 1024 + tid] = acc0;
  cat[lb * 1024 + tid + 256] = acc1;
  cat[lb * 1024 + 512 + tid] = hmid[lb * H + tid];
  cat[lb * 1024 + 768 + tid] = hmid[lb * H + tid + 256];
}

__global__ __launch_bounds__(256) void hattarg_kernel(
    const float* __restrict__ cat, const float* __restrict__ hattW,
    const float* __restrict__ hattb, float* __restrict__ h,
    const float* __restrict__ logits, const float* __restrict__ embed,
    float* __restrict__ emb) {
  __shared__ __align__(16) float smem[16 * 1024];
  int blk = blockIdx.x, tid = threadIdx.x;
  if (blk < 128) {
    int lbg = blk & 3, jg = blk >> 2;
    {
      const float4* cg2 = (const float4*)(cat + lbg * 16 * 1024);
      float4* s4 = (float4*)smem;
      for (int i = tid; i < 4096; i += 256) s4[i] = cg2[i];
    }
    __syncthreads();
    int ko = tid & 15, jl = tid >> 4;
    int j = jg * 16 + jl;
    const float* wrow = hattW + (size_t)j * 1024;
    float4 w[16];
#pragma unroll
    for (int kk = 0; kk < 16; ++kk) w[kk] = *(const float4*)&wrow[kk * 64 + ko * 4];
    float acc[16];
#pragma unroll
    for (int lb = 0; lb < 16; ++lb) acc[lb] = 0.f;
    for (int lb = 0; lb < 16; ++lb) {
      const float* cb = smem + lb * 1024;
#pragma unroll
      for (int kk = 0; kk < 16; ++kk)
        acc[lb] += dot4(*(const float4*)&cb[kk * 64 + ko * 4], w[kk]);
    }
#pragma unroll
    for (int lb = 0; lb < 16; ++lb) {
      acc[lb] += __shfl_xor(acc[lb], 1);
      acc[lb] += __shfl_xor(acc[lb], 2);
      acc[lb] += __shfl_xor(acc[lb], 4);
      acc[lb] += __shfl_xor(acc[lb], 8);
    }
    if (ko == 0) {
      float bias = hattb[j];
      for (int lb = 0; lb < 16; ++lb)
        h[(lbg * 16 + lb) * H + j] = tanhf(acc[lb] + bias);
    }
  } else {
    int b = blk - 128;
    float* sv = smem;
    int* si = (int*)(smem + 256);
    float best = -3.4e38f;
    int bi = 0x7fffffff;
    for (int it = 0; it < 10; ++it) {
      int v0 = it * 1024 + tid * 4;
      if (v0 < V) {
        float4 lv = *(const float4*)&logits[b * V + v0];
        if (lv.x > best) { best = lv.x; bi = v0; }
        if (lv.y > best) { best = lv.y; bi = v0 + 1; }
        if (lv.z > best) { best = lv.z; bi = v0 + 2; }
        if (lv.w > best) { best = lv.w; bi = v0 + 3; }
      }
    }
    sv[tid] = best; si[tid] = bi;
    __syncthreads();
    for (int st = 128; st > 0; st >>= 1) {
      if (tid < st) {
        float ov = sv[tid + st]; int oi = si[tid + st];
        if (ov > sv[tid] || (ov == sv[tid] && oi < si[tid])) { sv[tid] = ov; si[tid] = oi; }
      }
      __syncthreads();
    }
    int idx = si[0];
    for (int i = tid; i < H; i += 256) emb[b * H + i] = embed[(size_t)idx * H + i];
  }
}

__global__ __launch_bounds__(256) void finalize_kernel(
    const float* __restrict__ slog, float* __restrict__ outp) {
  int idx = blockIdx.x * 256 + threadIdx.x;
  float vals[T];
#pragma unroll
  for (int t = 0; t < T; ++t) vals[t] = slog[(size_t)t * (B * V) + idx];
#pragma unroll
  for (int t = 0; t < T; t += 4)
    *(float4*)&outp[(size_t)idx * T + t] =
        make_float4(vals[t], vals[t + 1], vals[t + 2], vals[t + 3]);
}

}  // namespace

extern "C" void kernel_launch(void* const* d_in, const int* in_sizes, int n_in,
                              void* d_out, int out_size, void* d_ws, size_t ws_size,
                              hipStream_t stream) {
  (void)in_sizes; (void)n_in; (void)out_size;
  const float* chan   = (const float*)d_in[0];
  const float* pooled = (const float*)d_in[1];
  const float* embed  = (const float*)d_in[2];
  const float* Wq     = (const float*)d_in[3];
  const float* bq     = (const float*)d_in[4];
  const float* Wk     = (const float*)d_in[5];
  const float* bk     = (const float*)d_in[6];
  const float* Wv     = (const float*)d_in[7];
  const float* bv     = (const float*)d_in[8];
  const float* Wih    = (const float*)d_in[9];
  const float* Whh    = (const float*)d_in[10];
  const float* bih    = (const float*)d_in[11];
  const float* bhh    = (const float*)d_in[12];
  const float* projW  = (const float*)d_in[13];
  const float* projb  = (const float*)d_in[14];
  const float* hattW  = (const float*)d_in[15];
  const float* hattb  = (const float*)d_in[16];
  const int*   sos    = (const int*)d_in[17];

  float* out = (float*)d_out;
  int*   bar = (int*)d_ws;                 // barrier region (first 2 KB)
  float* ws  = (float*)d_ws + 512;         // data region

  float* keysT   = ws;
  float* valuesT = keysT + B * S * 512;
  float* emb     = valuesT + B * S * 512;
  float* h       = emb + B * H;
  float* c       = h + L * B * H;
  float* hmid    = c + L * B * H;
  float* cat     = hmid + L * B * H;
  float* q       = cat + L * B * 1024;
  float* logits  = q + L * B * H;
  float* slog    = logits + B * V;

  size_t need_floats = 512 + (size_t)(slog - ws) + (size_t)T * B * V;
  bool fits = ws_size >= need_floats * sizeof(float);

  if (fits) {
    (void)hipMemsetAsync(d_ws, 0, 2048, stream);  // zero barrier counters
    KParams p = {chan, pooled, embed, Wq, bq, Wk, bk, Wv, bv,
                 Wih, Whh, bih, bhh, projW, projb, hattW, hattb,
                 sos, out, ws, bar};
    persist<<<NB, NT, 0, stream>>>(p);
    return;
  }

  // -------- fallback: previous verified multi-kernel path --------
  size_t base_floats = (size_t)(slog - ws) + 512;
  bool staged = ws_size >= (base_floats + (size_t)T * B * V) * sizeof(float);

  kv_kernel<<<256, 256, 0, stream>>>(chan, Wk, bk, Wv, bv, keysT, valuesT);
  init_kernel<<<(L * B * H) / 256, 256, 0, stream>>>(pooled, embed, sos, emb, h, c);
  {
    float* oc = staged ? slog : out;
    projq_kernel<<<625, 256, 0, stream>>>(emb, projW, projb, logits, oc,
                                          staged ? 0 : 1, 0,
                                          hmid, Wq, bq, q);
  }
  for (int t = 0; t < T - 1; ++t) {
    float* oc = staged ? (slog + (size_t)(t + 1) * B * V) : out;
    lstm_kernel<<<512, 256, 0, stream>>>(emb, h, c, Wih, Whh, bih, bhh, hmid, c);
    lstm_kernel<<<512, 256, 0, stream>>>(hmid, h + B * H, c + B * H,
                                         Wih + 4 * H * H, Whh + 4 * H * H,
                                         bih + 4 * H, bhh + 4 * H,
                                         hmid + B * H, c + B * H);
    projq_kernel<<<689, 256, 0, stream>>>(hmid + B * H, projW, projb, logits, oc,
                                          staged ? 0 : 1, t + 1,
                                          hmid, Wq, bq, q);
    sattn_kernel<<<L * B, 256, 0, stream>>>(q, keysT, valuesT, hmid, cat);
    hattarg_kernel<<<160, 256, 0, stream>>>(cat, hattW, hattb, h,
                                            logits, embed, emb);
  }
  if (staged) finalize_kernel<<<(B * V) / 256, 256, 0, stream>>>(slog, out);
}

// Round 6
// 2035.111 us; speedup vs baseline: 2.9586x; 1.9674x over previous
//
#include <hip/hip_runtime.h>

namespace {

constexpr int B = 32, H = 512, L = 2, T = 20, V = 10000, S = 49;

__device__ __forceinline__ float sigf(float x) { return 1.0f / (1.0f + expf(-x)); }
__device__ __forceinline__ float dot4(float4 a, float4 b) {
  return a.x*b.x + a.y*b.y + a.z*b.z + a.w*b.w;
}

// ---------------- setup: kv (blocks 0..255) + init (256..383) + slog[0] (384..1008)
__global__ __launch_bounds__(256) void setup_kernel(
    const float* __restrict__ chan,
    const float* __restrict__ Wk, const float* __restrict__ bk,
    const float* __restrict__ Wv, const float* __restrict__ bv,
    float* __restrict__ keysT, float* __restrict__ valuesT,
    const float* __restrict__ pooled, const float* __restrict__ embed,
    const int* __restrict__ sos,
    float* __restrict__ emb, float* __restrict__ h, float* __restrict__ c,
    const float* __restrict__ projW, const float* __restrict__ projb,
    float* __restrict__ slog0) {
  __shared__ __align__(16) float smem[8448];
  int blk = blockIdx.x, tid = threadIdx.x;
  if (blk < 256) {
    // ---- kv: verbatim kv_kernel body ----
    float* ch = smem;                 // 64*52
    float* wk = smem + 64 * 52;       // 49*52
    float* wv = wk + 49 * 52;         // 49*52
    int b = blk >> 3, dt = blk & 7;
    for (int i = tid; i < 49 * 49; i += 256) {
      int s = i / 49, j = i % 49;
      wk[s * 52 + j] = Wk[i]; wv[s * 52 + j] = Wv[i];
    }
    for (int i = tid; i < 64 * 49; i += 256) {
      int d = i / 49, j = i % 49;
      ch[d * 52 + j] = chan[((size_t)b * 512 + dt * 64 + d) * S + j];
    }
    __syncthreads();
    int dl = tid >> 2, sq = tid & 3;
    for (int s = sq; s < S; s += 4) {
      float ak = bk[s], av = bv[s];
      for (int j = 0; j < 49; ++j) {
        float cv = ch[dl * 52 + j];
        ak += cv * wk[s * 52 + j];
        av += cv * wv[s * 52 + j];
      }
      int d = dt * 64 + dl;
      keysT[((size_t)b * S + s) * H + d] = tanhf(ak);
      valuesT[((size_t)b * S + s) * H + d] = tanhf(av);
    }
  } else if (blk < 384) {
    // ---- init: verbatim init_kernel body ----
    int idx = (blk - 256) * 256 + tid;      // [0, 32768)
    float p = pooled[idx & (B * H - 1)];
    h[idx] = p;
    c[idx] = p;
    if (idx < B * H) emb[idx] = embed[(size_t)sos[0] * H + (idx & (H - 1))];
  } else {
    // ---- slog[0] = proj(embed[sos]) : batch-independent ----
    float* es = smem;                 // 512
    es[tid] = embed[(size_t)sos[0] * H + tid];
    es[tid + 256] = embed[(size_t)sos[0] * H + tid + 256];
    __syncthreads();
    int ko = tid & 15, vl = tid >> 4;
    int v = (blk - 384) * 16 + vl;
    const float* wrow = projW + (size_t)v * H;
    float4 w[8];
#pragma unroll
    for (int kk = 0; kk < 8; ++kk) w[kk] = *(const float4*)&wrow[kk * 64 + ko * 4];
    float acc = 0.f;
#pragma unroll
    for (int kk = 0; kk < 8; ++kk)
      acc += dot4(*(const float4*)&es[kk * 64 + ko * 4], w[kk]);
    acc += __shfl_xor(acc, 1);
    acc += __shfl_xor(acc, 2);
    acc += __shfl_xor(acc, 4);
    acc += __shfl_xor(acc, 8);
    if (ko == 0) {
      float r = acc + projb[v];
      for (int b = 0; b < 32; ++b) slog0[(size_t)b * V + v] = r;
    }
  }
}

// ---------------- LSTM cell (verbatim from verified baseline) ----------
__global__ __launch_bounds__(256) void lstm_kernel(
    const float* __restrict__ x, const float* __restrict__ hprev,
    const float* __restrict__ cprev,
    const float* __restrict__ Wih, const float* __restrict__ Whh,
    const float* __restrict__ bih, const float* __restrict__ bhh,
    float* __restrict__ hout, float* __restrict__ cout) {
  __shared__ __align__(16) float smem[32 * 512];   // 64 KB
  int tid = threadIdx.x;
  int hi = blockIdx.x;
  int ko = tid & 15, rr = (tid >> 4) & 3, bh = tid >> 6;
  {
    const float4* xg = (const float4*)x;
    float4* s4 = (float4*)smem;
    for (int i = tid; i < 4096; i += 256) s4[i] = xg[i];
  }
  __syncthreads();
  float acc[8];
#pragma unroll
  for (int j = 0; j < 8; ++j) acc[j] = 0.f;
  {
    const float* wrow = Wih + ((size_t)rr * H + hi) * H;
    float4 w[8];
#pragma unroll
    for (int kk = 0; kk < 8; ++kk) w[kk] = *(const float4*)&wrow[kk * 64 + ko * 4];
#pragma unroll
    for (int j = 0; j < 8; ++j) {
      const float* xb = smem + (bh * 8 + j) * 512;
#pragma unroll
      for (int kk = 0; kk < 8; ++kk)
        acc[j] += dot4(*(const float4*)&xb[kk * 64 + ko * 4], w[kk]);
    }
  }
  __syncthreads();
  {
    const float4* hg = (const float4*)hprev;
    float4* s4 = (float4*)smem;
    for (int i = tid; i < 4096; i += 256) s4[i] = hg[i];
  }
  __syncthreads();
  {
    const float* wrow = Whh + ((size_t)rr * H + hi) * H;
    float4 w[8];
#pragma unroll
    for (int kk = 0; kk < 8; ++kk) w[kk] = *(const float4*)&wrow[kk * 64 + ko * 4];
#pragma unroll
    for (int j = 0; j < 8; ++j) {
      const float* xb = smem + (bh * 8 + j) * 512;
#pragma unroll
      for (int kk = 0; kk < 8; ++kk)
        acc[j] += dot4(*(const float4*)&xb[kk * 64 + ko * 4], w[kk]);
    }
  }
  __syncthreads();
#pragma unroll
  for (int j = 0; j < 8; ++j) {
    acc[j] += __shfl_xor(acc[j], 1);
    acc[j] += __shfl_xor(acc[j], 2);
    acc[j] += __shfl_xor(acc[j], 4);
    acc[j] += __shfl_xor(acc[j], 8);
  }
  float* gbuf = smem;
  if (ko == 0) {
    float bias = bih[rr * H + hi] + bhh[rr * H + hi];
#pragma unroll
    for (int j = 0; j < 8; ++j) gbuf[rr * 32 + bh * 8 + j] = acc[j] + bias;
  }
  __syncthreads();
  if (tid < 32) {
    int b = tid;
    float gi = gbuf[b], gf = gbuf[32 + b], gg = gbuf[64 + b], go = gbuf[96 + b];
    float c2 = sigf(gf) * cprev[b * H + hi] + sigf(gi) * tanhf(gg);
    hout[b * H + hi] = sigf(go) * tanhf(c2);
    cout[b * H + hi] = c2;
  }
}

// ---------------- fused proj (blocks 0..624) + sattn-with-q (625..688) ----
__global__ __launch_bounds__(256) void projsat_kernel(
    const float* __restrict__ hmid_all,
    const float* __restrict__ projW, const float* __restrict__ projb,
    const float* __restrict__ Wq, const float* __restrict__ bq,
    const float* __restrict__ keysT, const float* __restrict__ valuesT,
    float* __restrict__ dst, float* __restrict__ cat) {
  __shared__ __align__(16) float smem[32 * 512];   // 64 KB
  int blk = blockIdx.x, tid = threadIdx.x;
  if (blk < 625) {
    // ---- proj of top-layer hmid -> dst (verbatim projq proj path, no logits) --
    const float* xin = hmid_all + B * H;
    {
      const float4* xg = (const float4*)xin;
      float4* s4 = (float4*)smem;
      for (int i = tid; i < 4096; i += 256) s4[i] = xg[i];
    }
    __syncthreads();
    int ko = tid & 15, vl = tid >> 4;
    int v = blk * 16 + vl;
    const float* wrow = projW + (size_t)v * H;
    float4 w[8];
#pragma unroll
    for (int kk = 0; kk < 8; ++kk) w[kk] = *(const float4*)&wrow[kk * 64 + ko * 4];
    float acc[32];
#pragma unroll
    for (int b = 0; b < 32; ++b) acc[b] = 0.f;
    for (int b = 0; b < 32; ++b) {
      const float* xb = smem + b * 512;
#pragma unroll
      for (int kk = 0; kk < 8; ++kk)
        acc[b] += dot4(*(const float4*)&xb[kk * 64 + ko * 4], w[kk]);
    }
#pragma unroll
    for (int b = 0; b < 32; ++b) {
      acc[b] += __shfl_xor(acc[b], 1);
      acc[b] += __shfl_xor(acc[b], 2);
      acc[b] += __shfl_xor(acc[b], 4);
      acc[b] += __shfl_xor(acc[b], 8);
    }
    if (ko == 0) {
      float bias = projb[v];
      for (int b = 0; b < 32; ++b) dst[(size_t)b * V + v] = acc[b] + bias;
    }
  } else {
    // ---- sattn for one lb, computing q in-block (same fp sequence as projq q) --
    int lb = blk - 625;               // 0..63
    int b = lb & 31, lg = lb >> 5;
    float* hr  = smem;                // 512
    float* qv  = smem + 512;          // 528 (4 chunks of 132, +4 skew)
    float* scl = smem + 1040;         // 64
    float* wts = smem + 1104;         // 64
    const float* hrow = hmid_all + (size_t)lg * B * H + (size_t)b * H;
    hr[tid] = hrow[tid];
    hr[tid + 256] = hrow[tid + 256];
    __syncthreads();
    int ko = tid & 15, vl = tid >> 4;
    for (int jg = 0; jg < 32; ++jg) {
      int j = jg * 16 + vl;
      const float* wrow = Wq + (size_t)j * H;
      float4 w[8];
#pragma unroll
      for (int kk = 0; kk < 8; ++kk) w[kk] = *(const float4*)&wrow[kk * 64 + ko * 4];
      float acc = 0.f;
#pragma unroll
      for (int kk = 0; kk < 8; ++kk)
        acc += dot4(*(const float4*)&hr[kk * 64 + ko * 4], w[kk]);
      acc += __shfl_xor(acc, 1);
      acc += __shfl_xor(acc, 2);
      acc += __shfl_xor(acc, 4);
      acc += __shfl_xor(acc, 8);
      if (ko == 0) qv[(j >> 7) * 132 + (j & 127)] = tanhf(acc + bq[j]);
    }
    __syncthreads();
    // ---- scores/softmax/attn: verbatim sattn_kernel ----
    int kq = tid & 3, sl = tid >> 2;
    float acc = 0.f;
    if (sl < S) {
      const float* kr = keysT + ((size_t)b * S + sl) * H + kq * 128;
      const float* qr = &qv[kq * 132];
      for (int k = 0; k < 128; k += 4)
        acc += dot4(*(const float4*)&qr[k], *(const float4*)&kr[k]);
    }
    acc += __shfl_xor(acc, 1);
    acc += __shfl_xor(acc, 2);
    if (kq == 0 && sl < S) scl[sl] = acc * (1.0f / 7.0f);
    __syncthreads();
    if (tid < 64) {
      float sc = (tid < S) ? scl[tid] : -3.4e38f;
      float m = sc;
      for (int o = 32; o > 0; o >>= 1) m = fmaxf(m, __shfl_xor(m, o));
      float e = (tid < S) ? expf(sc - m) : 0.f;
      float sum = e;
      for (int o = 32; o > 0; o >>= 1) sum += __shfl_xor(sum, o);
      if (tid < S) wts[tid] = e / sum;
    }
    __syncthreads();
    float acc0 = 0.f, acc1 = 0.f;
    for (int s = 0; s < S; ++s) {
      float w = wts[s];
      const float* vr = valuesT + ((size_t)b * S + s) * H;
      acc0 += w * vr[tid];
      acc1 += w * vr[tid + 256];
    }
    cat[lb * 1024 + tid] = acc0;
    cat[lb * 1024 + tid + 256] = acc1;
    cat[lb * 1024 + 512 + tid] = hmid_all[lb * H + tid];
    cat[lb * 1024 + 768 + tid] = hmid_all[lb * H + tid + 256];
  }
}

// ---------------- hatt (0..127) + argmax/embed (128..159); logits = slog slice --
__global__ __launch_bounds__(256) void hattarg_kernel(
    const float* __restrict__ cat, const float* __restrict__ hattW,
    const float* __restrict__ hattb, float* __restrict__ h,
    const float* __restrict__ logits, const float* __restrict__ embed,
    float* __restrict__ emb) {
  __shared__ __align__(16) float smem[16 * 1024];
  int blk = blockIdx.x, tid = threadIdx.x;
  if (blk < 128) {
    int lbg = blk & 3, jg = blk >> 2;
    {
      const float4* cg2 = (const float4*)(cat + lbg * 16 * 1024);
      float4* s4 = (float4*)smem;
      for (int i = tid; i < 4096; i += 256) s4[i] = cg2[i];
    }
    __syncthreads();
    int ko = tid & 15, jl = tid >> 4;
    int j = jg * 16 + jl;
    const float* wrow = hattW + (size_t)j * 1024;
    float4 w[16];
#pragma unroll
    for (int kk = 0; kk < 16; ++kk) w[kk] = *(const float4*)&wrow[kk * 64 + ko * 4];
    float acc[16];
#pragma unroll
    for (int lb = 0; lb < 16; ++lb) acc[lb] = 0.f;
    for (int lb = 0; lb < 16; ++lb) {
      const float* cb = smem + lb * 1024;
#pragma unroll
      for (int kk = 0; kk < 16; ++kk)
        acc[lb] += dot4(*(const float4*)&cb[kk * 64 + ko * 4], w[kk]);
    }
#pragma unroll
    for (int lb = 0; lb < 16; ++lb) {
      acc[lb] += __shfl_xor(acc[lb], 1);
      acc[lb] += __shfl_xor(acc[lb], 2);
      acc[lb] += __shfl_xor(acc[lb], 4);
      acc[lb] += __shfl_xor(acc[lb], 8);
    }
    if (ko == 0) {
      float bias = hattb[j];
      for (int lb = 0; lb < 16; ++lb)
        h[(lbg * 16 + lb) * H + j] = tanhf(acc[lb] + bias);
    }
  } else {
    int b = blk - 128;
    float* sv = smem;
    int* si = (int*)(smem + 256);
    float best = -3.4e38f;
    int bi = 0x7fffffff;
    for (int it = 0; it < 10; ++it) {
      int v0 = it * 1024 + tid * 4;
      if (v0 < V) {
        float4 lv = *(const float4*)&logits[(size_t)b * V + v0];
        if (lv.x > best) { best = lv.x; bi = v0; }
        if (lv.y > best) { best = lv.y; bi = v0 + 1; }
        if (lv.z > best) { best = lv.z; bi = v0 + 2; }
        if (lv.w > best) { best = lv.w; bi = v0 + 3; }
      }
    }
    sv[tid] = best; si[tid] = bi;
    __syncthreads();
    for (int st = 128; st > 0; st >>= 1) {
      if (tid < st) {
        float ov = sv[tid + st]; int oi = si[tid + st];
        if (ov > sv[tid] || (ov == sv[tid] && oi < si[tid])) { sv[tid] = ov; si[tid] = oi; }
      }
      __syncthreads();
    }
    int idx = si[0];
    for (int i = tid; i < H; i += 256) emb[b * H + i] = embed[(size_t)idx * H + i];
  }
}

// ---------------- final transpose: slog[t][b][v] -> out[b][v][t] ----------
__global__ __launch_bounds__(256) void finalize_kernel(
    const float* __restrict__ slog, float* __restrict__ outp) {
  int idx = blockIdx.x * 256 + threadIdx.x;   // b*V + v, exact 320000
  float vals[T];
#pragma unroll
  for (int t = 0; t < T; ++t) vals[t] = slog[(size_t)t * (B * V) + idx];
#pragma unroll
  for (int t = 0; t < T; t += 4)
    *(float4*)&outp[(size_t)idx * T + t] =
        make_float4(vals[t], vals[t + 1], vals[t + 2], vals[t + 3]);
}

// ============ fallback kernels (non-staged workspace): verified baseline =====

__global__ __launch_bounds__(256) void kv_kernel(
    const float* __restrict__ chan,
    const float* __restrict__ Wk, const float* __restrict__ bk,
    const float* __restrict__ Wv, const float* __restrict__ bv,
    float* __restrict__ keysT, float* __restrict__ valuesT) {
  __shared__ float ch[64][52];
  __shared__ float wk[49][52], wv[49][52];
  int b = blockIdx.x >> 3, dt = blockIdx.x & 7;
  int tid = threadIdx.x;
  for (int i = tid; i < 49 * 49; i += 256) {
    int s = i / 49, j = i % 49;
    wk[s][j] = Wk[i]; wv[s][j] = Wv[i];
  }
  for (int i = tid; i < 64 * 49; i += 256) {
    int d = i / 49, j = i % 49;
    ch[d][j] = chan[((size_t)b * 512 + dt * 64 + d) * S + j];
  }
  __syncthreads();
  int dl = tid >> 2, sq = tid & 3;
  for (int s = sq; s < S; s += 4) {
    float ak = bk[s], av = bv[s];
    for (int j = 0; j < 49; ++j) {
      float cv = ch[dl][j];
      ak += cv * wk[s][j];
      av += cv * wv[s][j];
    }
    int d = dt * 64 + dl;
    keysT[((size_t)b * S + s) * H + d] = tanhf(ak);
    valuesT[((size_t)b * S + s) * H + d] = tanhf(av);
  }
}

__global__ void init_kernel(const float* __restrict__ pooled,
                            const float* __restrict__ embed,
                            const int* __restrict__ sos,
                            float* __restrict__ emb, float* __restrict__ h,
                            float* __restrict__ c) {
  int idx = blockIdx.x * 256 + threadIdx.x;
  float p = pooled[idx & (B * H - 1)];
  h[idx] = p;
  c[idx] = p;
  if (idx < B * H) emb[idx] = embed[sos[0] * H + (idx & (H - 1))];
}

__global__ __launch_bounds__(256) void projq_kernel(
    const float* __restrict__ xin,
    const float* __restrict__ projW, const float* __restrict__ projb,
    float* __restrict__ logits, float* __restrict__ ocol, int direct, int tcol,
    const float* __restrict__ hmid_all, const float* __restrict__ Wq,
    const float* __restrict__ bq, float* __restrict__ q) {
  __shared__ __align__(16) float xs[32 * 512];
  int blk = blockIdx.x, tid = threadIdx.x;
  int ko = tid & 15, vl = tid >> 4;
  if (blk < 625) {
    {
      const float4* xg = (const float4*)xin;
      float4* s4 = (float4*)xs;
      for (int i = tid; i < 4096; i += 256) s4[i] = xg[i];
    }
    __syncthreads();
    int v = blk * 16 + vl;
    const float* wrow = projW + (size_t)v * H;
    float4 w[8];
#pragma unroll
    for (int kk = 0; kk < 8; ++kk) w[kk] = *(const float4*)&wrow[kk * 64 + ko * 4];
    float acc[32];
#pragma unroll
    for (int b = 0; b < 32; ++b) acc[b] = 0.f;
    for (int b = 0; b < 32; ++b) {
      const float* xb = xs + b * 512;
#pragma unroll
      for (int kk = 0; kk < 8; ++kk)
        acc[b] += dot4(*(const float4*)&xb[kk * 64 + ko * 4], w[kk]);
    }
#pragma unroll
    for (int b = 0; b < 32; ++b) {
      acc[b] += __shfl_xor(acc[b], 1);
      acc[b] += __shfl_xor(acc[b], 2);
      acc[b] += __shfl_xor(acc[b], 4);
      acc[b] += __shfl_xor(acc[b], 8);
    }
    if (ko == 0) {
      float bias = projb[v];
      for (int b = 0; b < 32; ++b) {
        float r = acc[b] + bias;
        logits[b * V + v] = r;
        if (direct) ocol[((size_t)b * V + v) * T + tcol] = r;
        else        ocol[b * V + v] = r;
      }
    }
  } else {
    int b2 = blk - 625;
    int lg = b2 & 1, jg = b2 >> 1;
    {
      const float4* xg = (const float4*)(hmid_all + lg * 32 * H);
      float4* s4 = (float4*)xs;
      for (int i = tid; i < 4096; i += 256) s4[i] = xg[i];
    }
    __syncthreads();
    int j = jg * 16 + vl;
    const float* wrow = Wq + (size_t)j * H;
    float4 w[8];
#pragma unroll
    for (int kk = 0; kk < 8; ++kk) w[kk] = *(const float4*)&wrow[kk * 64 + ko * 4];
    float acc[32];
#pragma unroll
    for (int b = 0; b < 32; ++b) acc[b] = 0.f;
    for (int b = 0; b < 32; ++b) {
      const float* xb = xs + b * 512;
#pragma unroll
      for (int kk = 0; kk < 8; ++kk)
        acc[b] += dot4(*(const float4*)&xb[kk * 64 + ko * 4], w[kk]);
    }
#pragma unroll
    for (int b = 0; b < 32; ++b) {
      acc[b] += __shfl_xor(acc[b], 1);
      acc[b] += __shfl_xor(acc[b], 2);
      acc[b] += __shfl_xor(acc[b], 4);
      acc[b] += __shfl_xor(acc[b], 8);
    }
    if (ko == 0) {
      float bias = bq[j];
      for (int b = 0; b < 32; ++b)
        q[(lg * 32 + b) * H + j] = tanhf(acc[b] + bias);
    }
  }
}

__global__ __launch_bounds__(256) void sattn_kernel(
    const float* __restrict__ q, const float* __restrict__ keysT,
    const float* __restrict__ valuesT, const float* __restrict__ hmid,
    float* __restrict__ cat) {
  __shared__ __align__(16) float qv[528];
  __shared__ float scl[64];
  __shared__ float wts[64];
  int lb = blockIdx.x, tid = threadIdx.x;
  int b = lb & 31;
  {
    int c0 = tid, c1 = tid + 256;
    qv[(c0 >> 7) * 132 + (c0 & 127)] = q[lb * H + c0];
    qv[(c1 >> 7) * 132 + (c1 & 127)] = q[lb * H + c1];
  }
  __syncthreads();
  int kq = tid & 3, sl = tid >> 2;
  float acc = 0.f;
  if (sl < S) {
    const float* kr = keysT + ((size_t)b * S + sl) * H + kq * 128;
    const float* qr = &qv[kq * 132];
    for (int k = 0; k < 128; k += 4)
      acc += dot4(*(const float4*)&qr[k], *(const float4*)&kr[k]);
  }
  acc += __shfl_xor(acc, 1);
  acc += __shfl_xor(acc, 2);
  if (kq == 0 && sl < S) scl[sl] = acc * (1.0f / 7.0f);
  __syncthreads();
  if (tid < 64) {
    float sc = (tid < S) ? scl[tid] : -3.4e38f;
    float m = sc;
    for (int o = 32; o > 0; o >>= 1) m = fmaxf(m, __shfl_xor(m, o));
    float e = (tid < S) ? expf(sc - m) : 0.f;
    float sum = e;
    for (int o = 32; o > 0; o >>= 1) sum += __shfl_xor(sum, o);
    if (tid < S) wts[tid] = e / sum;
  }
  __syncthreads();
  float acc0 = 0.f, acc1 = 0.f;
  for (int s = 0; s < S; ++s) {
    float w = wts[s];
    const float* vr = valuesT + ((size_t)b * S + s) * H;
    acc0 += w * vr[tid];
    acc1 += w * vr[tid + 256];
  }
  cat[lb * 1024 + tid] = acc0;
  cat[lb * 1024 + tid + 256] = acc1;
  cat[lb * 1024 + 512 + tid] = hmid[lb * H + tid];
  cat[lb * 1024 + 768 + tid] = hmid[lb * H + tid + 256];
}

}  // namespace

extern "C" void kernel_launch(void* const* d_in, const int* in_sizes, int n_in,
                              void* d_out, int out_size, void* d_ws, size_t ws_size,
                              hipStream_t stream) {
  (void)in_sizes; (void)n_in; (void)out_size;
  const float* chan   = (const float*)d_in[0];
  const float* pooled = (const float*)d_in[1];
  const float* embed  = (const float*)d_in[2];
  const float* Wq     = (const float*)d_in[3];
  const float* bq     = (const float*)d_in[4];
  const float* Wk     = (const float*)d_in[5];
  const float* bk     = (const float*)d_in[6];
  const float* Wv     = (const float*)d_in[7];
  const float* bv     = (const float*)d_in[8];
  const float* Wih    = (const float*)d_in[9];
  const float* Whh    = (const float*)d_in[10];
  const float* bih    = (const float*)d_in[11];
  const float* bhh    = (const float*)d_in[12];
  const float* projW  = (const float*)d_in[13];
  const float* projb  = (const float*)d_in[14];
  const float* hattW  = (const float*)d_in[15];
  const float* hattb  = (const float*)d_in[16];
  const int*   sos    = (const int*)d_in[17];

  float* out = (float*)d_out;
  float* ws  = (float*)d_ws;

  float* keysT   = ws;                        // B*S*512
  float* valuesT = keysT + B * S * 512;       // B*S*512
  float* emb     = valuesT + B * S * 512;     // B*H
  float* h       = emb + B * H;               // L*B*H
  float* c       = h + L * B * H;             // L*B*H
  float* hmid    = c + L * B * H;             // L*B*H
  float* cat     = hmid + L * B * H;          // L*B*1024
  float* q       = cat + L * B * 1024;        // L*B*H (fallback only)
  float* logits  = q + L * B * H;             // B*V   (fallback only)
  float* slog    = logits + B * V;            // T*B*V

  size_t base_floats = (size_t)(slog - ws);
  bool staged = ws_size >= (base_floats + (size_t)T * B * V) * sizeof(float);

  if (staged) {
    // ---- 77-dispatch path: setup + 19x(lstm,lstm,projsat[,hattarg]) + finalize
    setup_kernel<<<1009, 256, 0, stream>>>(chan, Wk, bk, Wv, bv, keysT, valuesT,
                                           pooled, embed, sos, emb, h, c,
                                           projW, projb, slog);
    for (int t = 0; t < T - 1; ++t) {
      float* dst = slog + (size_t)(t + 1) * B * V;
      lstm_kernel<<<512, 256, 0, stream>>>(emb, h, c, Wih, Whh, bih, bhh, hmid, c);
      lstm_kernel<<<512, 256, 0, stream>>>(hmid, h + B * H, c + B * H,
                                           Wih + 4 * H * H, Whh + 4 * H * H,
                                           bih + 4 * H, bhh + 4 * H,
                                           hmid + B * H, c + B * H);
      bool last = (t == T - 2);
      projsat_kernel<<<last ? 625 : 689, 256, 0, stream>>>(
          hmid, projW, projb, Wq, bq, keysT, valuesT, dst, cat);
      if (!last)
        hattarg_kernel<<<160, 256, 0, stream>>>(cat, hattW, hattb, h,
                                                dst, embed, emb);
    }
    finalize_kernel<<<(B * V) / 256, 256, 0, stream>>>(slog, out);
    return;
  }

  // -------- fallback: verified 5-dispatch/step path (direct out writes) -----
  kv_kernel<<<256, 256, 0, stream>>>(chan, Wk, bk, Wv, bv, keysT, valuesT);
  init_kernel<<<(L * B * H) / 256, 256, 0, stream>>>(pooled, embed, sos, emb, h, c);
  projq_kernel<<<625, 256, 0, stream>>>(emb, projW, projb, logits, out,
                                        1, 0, hmid, Wq, bq, q);
  for (int t = 0; t < T - 1; ++t) {
    lstm_kernel<<<512, 256, 0, stream>>>(emb, h, c, Wih, Whh, bih, bhh, hmid, c);
    lstm_kernel<<<512, 256, 0, stream>>>(hmid, h + B * H, c + B * H,
                                         Wih + 4 * H * H, Whh + 4 * H * H,
                                         bih + 4 * H, bhh + 4 * H,
                                         hmid + B * H, c + B * H);
    projq_kernel<<<689, 256, 0, stream>>>(hmid + B * H, projW, projb, logits, out,
                                          1, t + 1, hmid, Wq, bq, q);
    sattn_kernel<<<L * B, 256, 0, stream>>>(q, keysT, valuesT, hmid, cat);
    hattarg_kernel<<<160, 256, 0, stream>>>(cat, hattW, hattb, h,
                                            logits, embed, emb);
  }
}